// Round 11
// baseline (423.910 us; speedup 1.0000x reference)
//
#include <hip/hip_runtime.h>
#include <math.h>
#include <cstddef>

// Problem constants
#define LQ   19200          // NL*H*W tokens
#define HH   40
#define WW   120
#define HWp  4800
#define CCh  128
#define NHd  8
#define NLv  4
#define NPt  4
#define RHs  80
#define RWs  240

typedef __attribute__((ext_vector_type(8))) short bf16x8;
typedef __attribute__((ext_vector_type(4))) float f32x4;
typedef __attribute__((ext_vector_type(8))) _Float16 h16x8;
typedef __attribute__((address_space(1))) const unsigned int GUI;
typedef __attribute__((address_space(3))) unsigned int LUI;

__device__ inline unsigned short f2bf(float f) {
    unsigned int u = __float_as_uint(f);
    u += 0x7fffu + ((u >> 16) & 1u);        // round-to-nearest-even
    return (unsigned short)(u >> 16);
}
__device__ inline float bf2f(unsigned int lo16) { return __uint_as_float(lo16 << 16); }

// sine pos-embed from small tables: pos(row, col) = tab + lvl_emb
__device__ inline float pos_eval(const float* __restrict__ ty,
                                 const float* __restrict__ tx,
                                 const float* __restrict__ lvl,
                                 int row, int col)
{
    int n = row / HWp, pix = row % HWp;
    int hh = pix / WW, wx = pix % WW;
    float t = (col < 64) ? ty[hh * 64 + col] : tx[wx * 64 + (col - 64)];
    return t + lvl[n * CCh + col];
}

// ---------------------------------------------------------------------------
// bf16 MFMA GEMM: Out[M,N] = A[M,K] @ Bw[N,K]^T + bias, opt relu.
// Double-buffered LDS K-loop. BMD ∈ {64,128}: block-M tile (64 doubles the
// grid for small GEMMs — latency hiding by block count).
// BIAS_ROW: bias indexed by row (weights-as-A transposed trick).
// OMODE: 0 = fp32 OutF; 1 = bf16 OutB; 2 = both.
// ---------------------------------------------------------------------------
template<bool BIAS_ROW, bool RELU, int OMODE, int BMD>
__global__ __launch_bounds__(256) void gemm_bf16(
    const unsigned short* __restrict__ A,
    const unsigned short* __restrict__ Bw,
    const float* __restrict__ bias,
    float* __restrict__ OutF, unsigned short* __restrict__ OutB,
    int M, int N, int K)
{
    constexpr int BN = 64, BK = 32;
    constexpr int MI = BMD / 32;                 // row-tiles per wave
    __shared__ unsigned short As[2][BMD * BK];   // row-major [m][k]
    __shared__ unsigned short Bs[2][BN * BK];
    const int bm = blockIdx.y * BMD, bn = blockIdx.x * BN;
    const int tid = threadIdx.x;
    const int wid = tid >> 6, lane = tid & 63;
    const int wm = (wid & 1) * (BMD / 2), wn = (wid >> 1) * 32;
    const int lm = lane & 15, lqd = lane >> 4;

    f32x4 acc[MI][2] = {};

    const int arow = lane >> 2;          // 0..15 within a 16-row chunk
    const int akc  = (lane & 3) * 8;     // k element offset (16 B granules)
    const unsigned short* aG0;
    const unsigned short* aG1 = nullptr;
    if constexpr (BMD == 128) {
        aG0 = A + (size_t)(bm + wid * 32 +      arow) * K + akc;
        aG1 = A + (size_t)(bm + wid * 32 + 16 + arow) * K + akc;
    } else {
        aG0 = A + (size_t)(bm + wid * 16 + arow) * K + akc;
    }
    const unsigned short* bG = Bw + (size_t)(bn + wid * 16 + arow) * K + akc;
    const int aoff = (BMD == 128) ? (wid * 1024 + lane * 8) : (wid * 512 + lane * 8);
    const int boff = wid * 512 + lane * 8;

    auto stage = [&](int b, int k0) {
        __builtin_amdgcn_global_load_lds((GUI*)(aG0 + k0), (LUI*)(As[b] + aoff), 16, 0, 0);
        if constexpr (BMD == 128)
            __builtin_amdgcn_global_load_lds((GUI*)(aG1 + k0), (LUI*)(As[b] + aoff + 512), 16, 0, 0);
        __builtin_amdgcn_global_load_lds((GUI*)(bG + k0), (LUI*)(Bs[b] + boff), 16, 0, 0);
    };

    stage(0, 0);
    __syncthreads();
    int buf = 0;
    for (int k0 = 0; k0 < K; k0 += BK, buf ^= 1) {
        if (k0 + BK < K) stage(buf ^ 1, k0 + BK);
        bf16x8 a[MI], b[2];
        #pragma unroll
        for (int i = 0; i < MI; i++)
            a[i] = *(const bf16x8*)(As[buf] + (wm + i * 16 + lm) * BK + lqd * 8);
        #pragma unroll
        for (int j = 0; j < 2; j++)
            b[j] = *(const bf16x8*)(Bs[buf] + (wn + j * 16 + lm) * BK + lqd * 8);
        #pragma unroll
        for (int i = 0; i < MI; i++)
            #pragma unroll
            for (int j = 0; j < 2; j++)
                acc[i][j] = __builtin_amdgcn_mfma_f32_16x16x32_bf16(a[i], b[j], acc[i][j], 0, 0, 0);
        __syncthreads();
    }

    #pragma unroll
    for (int i = 0; i < MI; i++) {
        int row0 = bm + wm + i * 16 + lqd * 4;
        #pragma unroll
        for (int j = 0; j < 2; j++) {
            int col = bn + wn + j * 16 + lm;
            float bc = BIAS_ROW ? 0.f : bias[col];
            #pragma unroll
            for (int r = 0; r < 4; r++) {
                int row = row0 + r;
                float v = acc[i][j][r] + (BIAS_ROW ? bias[row] : bc);
                if (RELU) v = fmaxf(v, 0.f);
                size_t o = (size_t)row * N + col;
                if (OMODE == 0) OutF[o] = v;
                else if (OMODE == 1) OutB[o] = f2bf(v);
                else { OutF[o] = v; OutB[o] = f2bf(v); }
            }
        }
    }
}

// ---------------------------------------------------------------------------
// Merged off/attn + val GEMM for one layer. Grid dim3(8, 300), BM=64, K=128.
// Double-buffered LDS. BM=64 doubles blocks (1200->2400) at identical global
// traffic — these small GEMMs are latency-hidden by block count (R8 lesson).
// bx<6: A=qb, W=Woa(384x128): col<256 -> fp16 off (stride 256);
//       col>=256 -> softmax16 -> fp16 attn (stride 128).
// bx>=6: A=srcb, W=Wv(128x128): bf16 val in plane layout [l][h][4800][16].
// ---------------------------------------------------------------------------
__global__ __launch_bounds__(256) void gemm_oav(
    const unsigned short* __restrict__ Aq,
    const unsigned short* __restrict__ Asrc,
    const unsigned short* __restrict__ Woa, const float* __restrict__ boa,
    const unsigned short* __restrict__ Wv,  const float* __restrict__ bv,
    _Float16* __restrict__ OutH, _Float16* __restrict__ OutH2,
    unsigned short* __restrict__ OutV)
{
    constexpr int BK = 32, K = 128;
    __shared__ unsigned short As[2][64 * BK];
    __shared__ unsigned short Bs[2][64 * BK];
    const int bx = blockIdx.x;
    const bool isv = bx >= 6;
    const unsigned short* A  = isv ? Asrc : Aq;
    const unsigned short* Bw = isv ? Wv : Woa;
    const float* bias = isv ? bv : boa;
    const int bn = isv ? (bx - 6) * 64 : bx * 64;
    const int bm = blockIdx.y * 64;
    const int tid = threadIdx.x;
    const int wid = tid >> 6, lane = tid & 63;
    const int wm = (wid & 1) * 32, wn = (wid >> 1) * 32;
    const int lm = lane & 15, lqd = lane >> 4;

    f32x4 acc[2][2] = {};

    const int arow = lane >> 2;
    const int akc  = (lane & 3) * 8;
    const unsigned short* aG = A  + (size_t)(bm + wid * 16 + arow) * K + akc;
    const unsigned short* bG = Bw + (size_t)(bn + wid * 16 + arow) * K + akc;
    const int loff = wid * 512 + lane * 8;

    auto stage = [&](int b, int k0) {
        __builtin_amdgcn_global_load_lds((GUI*)(aG + k0), (LUI*)(As[b] + loff), 16, 0, 0);
        __builtin_amdgcn_global_load_lds((GUI*)(bG + k0), (LUI*)(Bs[b] + loff), 16, 0, 0);
    };

    stage(0, 0);
    __syncthreads();
    int buf = 0;
    for (int k0 = 0; k0 < K; k0 += BK, buf ^= 1) {
        if (k0 + BK < K) stage(buf ^ 1, k0 + BK);
        bf16x8 a[2], b[2];
        #pragma unroll
        for (int i = 0; i < 2; i++)
            a[i] = *(const bf16x8*)(As[buf] + (wm + i * 16 + lm) * BK + lqd * 8);
        #pragma unroll
        for (int j = 0; j < 2; j++)
            b[j] = *(const bf16x8*)(Bs[buf] + (wn + j * 16 + lm) * BK + lqd * 8);
        #pragma unroll
        for (int i = 0; i < 2; i++)
            #pragma unroll
            for (int j = 0; j < 2; j++)
                acc[i][j] = __builtin_amdgcn_mfma_f32_16x16x32_bf16(a[i], b[j], acc[i][j], 0, 0, 0);
        __syncthreads();
    }

    #pragma unroll
    for (int i = 0; i < 2; i++) {
        int row0 = bm + wm + i * 16 + lqd * 4;
        #pragma unroll
        for (int j = 0; j < 2; j++) {
            int col = bn + wn + j * 16 + lm;
            float bc = bias[col];
            if (!isv) {
                if (col < 256) {
                    #pragma unroll
                    for (int r = 0; r < 4; r++)
                        OutH[(size_t)(row0 + r) * 256 + col] = (_Float16)(acc[i][j][r] + bc);
                } else {
                    #pragma unroll
                    for (int r = 0; r < 4; r++) {
                        float v = acc[i][j][r] + bc;
                        float m = v;
                        #pragma unroll
                        for (int msk = 1; msk < 16; msk <<= 1)
                            m = fmaxf(m, __shfl_xor(m, msk));
                        float e = __expf(v - m);
                        float s = e;
                        #pragma unroll
                        for (int msk = 1; msk < 16; msk <<= 1)
                            s += __shfl_xor(s, msk);
                        OutH2[(size_t)(row0 + r) * 128 + (col - 256)] = (_Float16)(e / s);
                    }
                }
            } else {
                #pragma unroll
                for (int r = 0; r < 4; r++) {
                    int row = row0 + r;
                    int plane = (row / HWp) * 8 + (col >> 4);
                    size_t o = ((size_t)plane * HWp + (row % HWp)) * 16 + (col & 15);
                    OutV[o] = f2bf(acc[i][j][r] + bc);
                }
            }
        }
    }
}

// ---------------------------------------------------------------------------
// Fully-fused post-attention block, per 32-token block (4 waves).
// Weights Wout/Wff1/Wff2 in MFMA FRAGMENT LAYOUT [n0][kc][lqd][lm][8]
// (prepped by prep_all): every b-fragment load is a contiguous 1 KB wave read.
// ff dim processed in 4 chunks of 128 (R4 shape: fs 8.7 KB, LDS 18.4 KB —
// measured <39.6 us; the 2x256 variant regressed to 46.6 us, R10):
//   delta1 = attnout @ W_out^T + b_out
//   y1 = LayerNorm(src + delta1) * g1 + c1
//   for qc in 0..3: f = relu(y1 @ Wff1[qc]^T + b); delta2 += f @ Wff2[:,qc]^T
//   y2 = LayerNorm(y1 + delta2 + bff2) * g2 + c2
// WQ: also write qb = bf16(y2 + pos(row,col)) from ty/tx/lvl tables.
// WMERGE: write only merge-layout bf16 mergeb[pix][n*128+c] (final layer).
// ---------------------------------------------------------------------------
template<bool WQ, bool WMERGE>
__global__ __launch_bounds__(256) void attn_ff(
    const unsigned short* __restrict__ attnout, const float* __restrict__ srcF_in,
    const unsigned short* __restrict__ Wout, const float* __restrict__ bout,
    const float* __restrict__ g1, const float* __restrict__ c1,
    const unsigned short* __restrict__ Wff1, const float* __restrict__ bff1,
    const unsigned short* __restrict__ Wff2, const float* __restrict__ bff2,
    const float* __restrict__ g2, const float* __restrict__ c2,
    float* __restrict__ outF, unsigned short* __restrict__ outB,
    const float* __restrict__ ty, const float* __restrict__ tx,
    const float* __restrict__ lvl, unsigned short* __restrict__ qb,
    unsigned short* __restrict__ mergeb)
{
    __shared__ unsigned short fs[32 * 136];     //  8,704 B ff activation chunk
    __shared__ unsigned short y1s[32 * 136];    //  8,704 B LN1 output (bf16)
    __shared__ float red[4][2][32];             //  1,024 B cross-wave LN partials
    const int bm = blockIdx.x * 32;
    const int tid = threadIdx.x;
    const int wid = tid >> 6, lane = tid & 63;
    const int lm = lane & 15, lqd = lane >> 4;
    const int wn2 = wid * 32;                   // col ownership, phases A & C

    // ---- Phase A: delta1 = attnout @ Wout^T (cols wn2..wn2+32)
    float y1r[2][2][4];
    {
        f32x4 accA[2][2] = {};
        for (int k0 = 0; k0 < 128; k0 += 32) {
            int kc = k0 >> 5;
            bf16x8 a[2], b[2];
            #pragma unroll
            for (int i = 0; i < 2; i++)
                a[i] = *(const bf16x8*)(attnout + (size_t)(bm + i * 16 + lm) * 128 + k0 + lqd * 8);
            #pragma unroll
            for (int j = 0; j < 2; j++)
                b[j] = *(const bf16x8*)(Wout + ((size_t)((wid * 2 + j) * 4 + kc) * 64 + lane) * 8);
            #pragma unroll
            for (int i = 0; i < 2; i++)
                #pragma unroll
                for (int j = 0; j < 2; j++)
                    accA[i][j] = __builtin_amdgcn_mfma_f32_16x16x32_bf16(a[i], b[j], accA[i][j], 0, 0, 0);
        }
        #pragma unroll
        for (int i = 0; i < 2; i++)
            #pragma unroll
            for (int j = 0; j < 2; j++) {
                int col = wn2 + j * 16 + lm;
                float bc = bout[col];
                #pragma unroll
                for (int r = 0; r < 4; r++) {
                    int row = bm + i * 16 + lqd * 4 + r;
                    y1r[i][j][r] = accA[i][j][r] + bc + srcF_in[(size_t)row * 128 + col];
                }
            }
    }
    // LN1 stats
    #pragma unroll
    for (int i = 0; i < 2; i++) {
        #pragma unroll
        for (int r = 0; r < 4; r++) {
            float s = y1r[i][0][r] + y1r[i][1][r];
            float q = y1r[i][0][r] * y1r[i][0][r] + y1r[i][1][r] * y1r[i][1][r];
            #pragma unroll
            for (int msk = 1; msk < 16; msk <<= 1) {
                s += __shfl_xor(s, msk);
                q += __shfl_xor(q, msk);
            }
            if (lm == 0) {
                int rl = i * 16 + lqd * 4 + r;
                red[wid][0][rl] = s;
                red[wid][1][rl] = q;
            }
        }
    }
    __syncthreads();
    #pragma unroll
    for (int i = 0; i < 2; i++) {
        float mean[4], inv[4];
        #pragma unroll
        for (int r = 0; r < 4; r++) {
            int rl = i * 16 + lqd * 4 + r;
            float s = red[0][0][rl] + red[1][0][rl] + red[2][0][rl] + red[3][0][rl];
            float q = red[0][1][rl] + red[1][1][rl] + red[2][1][rl] + red[3][1][rl];
            float m = s * (1.0f / 128.0f);
            float v = q * (1.0f / 128.0f) - m * m;
            mean[r] = m;
            inv[r] = rsqrtf(v + 1e-5f);
        }
        #pragma unroll
        for (int j = 0; j < 2; j++) {
            int col = wn2 + j * 16 + lm;
            float gc = g1[col], bc = c1[col];
            #pragma unroll
            for (int r = 0; r < 4; r++) {
                float y = (y1r[i][j][r] - mean[r]) * inv[r] * gc + bc;
                y1r[i][j][r] = y;
                y1s[(i * 16 + lqd * 4 + r) * 136 + col] = f2bf(y);
            }
        }
    }
    __syncthreads();

    // ---- Phases B+C, chunked over ff dim (4 chunks of 128)
    f32x4 acc2[2][2] = {};
    for (int qc = 0; qc < 4; qc++) {
        // Phase B chunk: f = relu(y1 @ Wff1[qc*128 + wid*32 ..]^T + b)
        {
            f32x4 accB[2][2] = {};
            for (int k0 = 0; k0 < 128; k0 += 32) {
                int kc = k0 >> 5;
                bf16x8 a[2], b[2];
                #pragma unroll
                for (int i = 0; i < 2; i++)
                    a[i] = *(const bf16x8*)(y1s + (i * 16 + lm) * 136 + k0 + lqd * 8);
                #pragma unroll
                for (int j = 0; j < 2; j++)
                    b[j] = *(const bf16x8*)(Wff1 + ((size_t)((qc * 8 + wid * 2 + j) * 4 + kc) * 64 + lane) * 8);
                #pragma unroll
                for (int i = 0; i < 2; i++)
                    #pragma unroll
                    for (int j = 0; j < 2; j++)
                        accB[i][j] = __builtin_amdgcn_mfma_f32_16x16x32_bf16(a[i], b[j], accB[i][j], 0, 0, 0);
            }
            #pragma unroll
            for (int i = 0; i < 2; i++) {
                #pragma unroll
                for (int j = 0; j < 2; j++) {
                    int col = wid * 32 + j * 16 + lm;            // 0..127 within chunk
                    float bc = bff1[qc * 128 + col];
                    #pragma unroll
                    for (int r = 0; r < 4; r++) {
                        int row = i * 16 + lqd * 4 + r;
                        fs[row * 136 + col] = f2bf(fmaxf(accB[i][j][r] + bc, 0.f));
                    }
                }
            }
        }
        __syncthreads();
        // Phase C chunk: acc2 += f @ Wff2[wn2.., qc*128..]^T
        for (int k0 = 0; k0 < 128; k0 += 32) {
            int kc = qc * 4 + (k0 >> 5);       // global k-chunk in K=512
            bf16x8 a[2], b[2];
            #pragma unroll
            for (int i = 0; i < 2; i++)
                a[i] = *(const bf16x8*)(fs + (i * 16 + lm) * 136 + k0 + lqd * 8);
            #pragma unroll
            for (int j = 0; j < 2; j++)
                b[j] = *(const bf16x8*)(Wff2 + ((size_t)((wid * 2 + j) * 16 + kc) * 64 + lane) * 8);
            #pragma unroll
            for (int i = 0; i < 2; i++)
                #pragma unroll
                for (int j = 0; j < 2; j++)
                    acc2[i][j] = __builtin_amdgcn_mfma_f32_16x16x32_bf16(a[i], b[j], acc2[i][j], 0, 0, 0);
        }
        __syncthreads();   // fs dead; next chunk may overwrite
    }

    // z2 = delta2 + bias + y1 (registers), LN2
    float z[2][2][4];
    #pragma unroll
    for (int i = 0; i < 2; i++) {
        #pragma unroll
        for (int j = 0; j < 2; j++) {
            int col = wn2 + j * 16 + lm;
            float bc = bff2[col];
            #pragma unroll
            for (int r = 0; r < 4; r++)
                z[i][j][r] = acc2[i][j][r] + bc + y1r[i][j][r];
        }
    }
    #pragma unroll
    for (int i = 0; i < 2; i++) {
        #pragma unroll
        for (int r = 0; r < 4; r++) {
            float s = z[i][0][r] + z[i][1][r];
            float q = z[i][0][r] * z[i][0][r] + z[i][1][r] * z[i][1][r];
            #pragma unroll
            for (int msk = 1; msk < 16; msk <<= 1) {
                s += __shfl_xor(s, msk);
                q += __shfl_xor(q, msk);
            }
            if (lm == 0) {
                int rl = i * 16 + lqd * 4 + r;
                red[wid][0][rl] = s;
                red[wid][1][rl] = q;
            }
        }
    }
    __syncthreads();

    #pragma unroll
    for (int i = 0; i < 2; i++) {
        float mean[4], inv[4];
        #pragma unroll
        for (int r = 0; r < 4; r++) {
            int rl = i * 16 + lqd * 4 + r;
            float s = red[0][0][rl] + red[1][0][rl] + red[2][0][rl] + red[3][0][rl];
            float q = red[0][1][rl] + red[1][1][rl] + red[2][1][rl] + red[3][1][rl];
            float m = s * (1.0f / 128.0f);
            float v = q * (1.0f / 128.0f) - m * m;
            mean[r] = m;
            inv[r] = rsqrtf(v + 1e-5f);
        }
        #pragma unroll
        for (int j = 0; j < 2; j++) {
            int col = wn2 + j * 16 + lm;
            float gc = g2[col], bc2 = c2[col];
            #pragma unroll
            for (int r = 0; r < 4; r++) {
                int row = bm + i * 16 + lqd * 4 + r;
                float y = (z[i][j][r] - mean[r]) * inv[r] * gc + bc2;
                if constexpr (WMERGE) {
                    int n = row / HWp, pix = row % HWp;
                    mergeb[(size_t)pix * 512 + n * 128 + col] = f2bf(y);
                } else {
                    size_t o = (size_t)row * 128 + col;
                    outF[o] = y;
                    outB[o] = f2bf(y);
                    if constexpr (WQ)
                        qb[o] = f2bf(y + pos_eval(ty, tx, lvl, row, col));
                }
            }
        }
    }
}

// ---------------------------------------------------------------------------
// Implicit-GEMM 3x3 conv from padded NHWC bf16 input, tap-major weights.
// BM=64 (grid 2x300 = 600 blocks). Double-buffered LDS chunk loop.
// MODE 0: dconv  — X:(4,82,242,128), stride 2, out: src fp32 + srcb bf16 +
//                  qb = bf16(src+pos(tables)), relu.
// MODE 1: uconv  — X:(82,242,128), stride 1, out: d_out fp32 (128,19200)
//                  via LDS-transposed store, relu.
// ---------------------------------------------------------------------------
template<int MODE>
__global__ __launch_bounds__(256) void conv3x3_gemm(
    const unsigned short* __restrict__ X,
    const unsigned short* __restrict__ Wp,
    const float* __restrict__ bias,
    float* __restrict__ OutF, unsigned short* __restrict__ OutB,
    const float* __restrict__ ty, const float* __restrict__ tx,
    const float* __restrict__ lvl, unsigned short* __restrict__ Qb)
{
    constexpr int BM = 64, BN = 64, BK = 32;
    constexpr int SMEM = (MODE == 1) ? 17408 : 16384;   // dbuf A/B = 16 KB; Ts = 17,408 B
    __shared__ __align__(16) unsigned char smem[SMEM];
    unsigned short* As = (unsigned short*)smem;            // [2][64*32]
    unsigned short* Bs = (unsigned short*)(smem + 8192);   // [2][64*32]
    const int bm = blockIdx.y * BM, bn = blockIdx.x * BN;
    const int tid = threadIdx.x;
    const int wid = tid >> 6, lane = tid & 63;
    const int wm = (wid & 1) * 32, wn = (wid >> 1) * 32;
    const int lm = lane & 15, lqd = lane >> 4;

    f32x4 acc[2][2] = {};

    const int arow = lane >> 2;
    const int akc  = (lane & 3) * 8;
    const int r0 = bm + wid * 16 + arow;
    size_t bA0;
    if (MODE == 0) {
        int n0 = r0 / HWp, rem0 = r0 % HWp, oh0 = rem0 / WW, ow0 = rem0 % WW;
        bA0 = ((size_t)(n0 * 82 + oh0 * 2) * 242 + ow0 * 2) * 128;
    } else {
        int y0 = r0 / RWs, x0 = r0 % RWs;
        bA0 = ((size_t)y0 * 242 + x0) * 128;
    }
    const unsigned short* bG = Wp + (size_t)(bn + wid * 16 + arow) * 1152 + akc;
    const int loff = wid * 512 + lane * 8;

    auto stage = [&](int b, int c) {
        int tap = c >> 2;
        int cpart = (c & 3) << 5;
        int ky = tap / 3, kx = tap % 3;
        int toff = (ky * 242 + kx) * 128 + cpart + akc;
        __builtin_amdgcn_global_load_lds((GUI*)(X + bA0 + toff), (LUI*)(As + b * 2048 + loff), 16, 0, 0);
        __builtin_amdgcn_global_load_lds((GUI*)(bG + c * 32), (LUI*)(Bs + b * 2048 + loff), 16, 0, 0);
    };

    stage(0, 0);
    __syncthreads();
    int buf = 0;
    for (int chunk = 0; chunk < 36; chunk++, buf ^= 1) {
        if (chunk < 35) stage(buf ^ 1, chunk + 1);
        bf16x8 a[2], b[2];
        #pragma unroll
        for (int i = 0; i < 2; i++)
            a[i] = *(const bf16x8*)(As + buf * 2048 + (wm + i * 16 + lm) * BK + lqd * 8);
        #pragma unroll
        for (int j = 0; j < 2; j++)
            b[j] = *(const bf16x8*)(Bs + buf * 2048 + (wn + j * 16 + lm) * BK + lqd * 8);
        #pragma unroll
        for (int i = 0; i < 2; i++)
            #pragma unroll
            for (int j = 0; j < 2; j++)
                acc[i][j] = __builtin_amdgcn_mfma_f32_16x16x32_bf16(a[i], b[j], acc[i][j], 0, 0, 0);
        __syncthreads();
    }

    if (MODE == 0) {
        #pragma unroll
        for (int i = 0; i < 2; i++) {
            int row0 = bm + wm + i * 16 + lqd * 4;
            #pragma unroll
            for (int j = 0; j < 2; j++) {
                int col = bn + wn + j * 16 + lm;
                float bc = bias[col];
                #pragma unroll
                for (int r = 0; r < 4; r++) {
                    int row = row0 + r;
                    float v = fmaxf(acc[i][j][r] + bc, 0.f);
                    size_t o = (size_t)row * 128 + col;
                    OutF[o] = v;
                    OutB[o] = f2bf(v);
                    Qb[o] = f2bf(v + pos_eval(ty, tx, lvl, row, col));
                }
            }
        }
    } else {
        float* Ts = (float*)smem;                 // 64 ch x 68 pix floats
        #pragma unroll
        for (int i = 0; i < 2; i++) {
            int lr0 = wm + i * 16 + lqd * 4;
            #pragma unroll
            for (int j = 0; j < 2; j++) {
                int lc = wn + j * 16 + lm;
                float bc = bias[bn + lc];
                #pragma unroll
                for (int r = 0; r < 4; r++)
                    Ts[lc * 68 + lr0 + r] = fmaxf(acc[i][j][r] + bc, 0.f);
            }
        }
        __syncthreads();
        for (int f = tid; f < 64 * 16; f += 256) {
            int ch = f >> 4, p4 = (f & 15) << 2;
            float4 v4 = *(const float4*)(Ts + ch * 68 + p4);
            *(float4*)(OutF + (size_t)(bn + ch) * 19200 + bm + p4) = v4;
        }
    }
}

// ---------------------------------------------------------------------------
// One-dispatch prep: linear weights -> bf16 (Wout/Wff1/Wff2 in MFMA fragment
// layout [n0][kc][lqd][lm][8]), [W_off;W_attn] concat, conv weights
// tap-major, halo zero, pos sin/cos TABLES (ty 40x64, tx 120x64), and the
// NCHW->NHWC input transpose.
// ---------------------------------------------------------------------------
__global__ __launch_bounds__(256) void prep_all(
    const float* __restrict__ W_val, const float* __restrict__ W_out,
    const float* __restrict__ W_ff1, const float* __restrict__ W_ff2,
    const float* __restrict__ merge_w,
    const float* __restrict__ Woff, const float* __restrict__ boff,
    const float* __restrict__ Wattn, const float* __restrict__ battn,
    const float* __restrict__ dconv_w, const float* __restrict__ uconv_w,
    const float* __restrict__ x,
    unsigned short* __restrict__ wb, unsigned short* __restrict__ wcat,
    float* __restrict__ bcat, unsigned short* __restrict__ dconv_wb,
    unsigned short* __restrict__ uconv_wb, unsigned short* __restrict__ xp,
    float* __restrict__ ty, float* __restrict__ tx)
{
    __shared__ unsigned short t[240 * 36];       // used by transpose blocks only
    int blk = blockIdx.x;
    if (blk >= 4271) {
        // NCHW fp32 (4,128,80,240) -> padded NHWC bf16 (4,82,242,128)
        int b = blk - 4271;                      // < 1280: (n, y, 32-ch tile)
        int ct = b & 3;
        int tmp = b >> 2;
        int y = tmp % 80, n = tmp / 80;
        const float* xin = x + (((size_t)(n * 128 + ct * 32)) * 80 + y) * 240;
        for (int f = threadIdx.x; f < 32 * 240; f += 256) {
            int c = f / 240, xc = f % 240;
            t[xc * 36 + c] = f2bf(xin[(size_t)c * 19200 + xc]);
        }
        __syncthreads();
        unsigned short* out = xp + (((size_t)(n * 82 + y + 1)) * 242 + 1) * 128 + ct * 32;
        for (int f = threadIdx.x; f < 240 * 8; f += 256) {
            int xc = f >> 3, c4 = (f & 7) << 2;
            ushort4 v = *(const ushort4*)(t + xc * 36 + c4);
            *(ushort4*)(out + (size_t)xc * 128 + c4) = v;
        }
        return;
    }
    int idx = blk * 256 + threadIdx.x;
    if (idx < 557056) {
        if (idx < 49152) {
            wb[idx] = f2bf(W_val[idx]);                      // row-major (gemm_oav)
        } else if (idx < 98304) {
            int rel = idx - 49152;                           // W_out: N=128,K=128
            int layer = rel >> 14, within = rel & 16383;
            int n = within >> 7, k = within & 127;
            int frag = ((((n >> 4) * 4 + (k >> 5)) * 4 + ((k >> 3) & 3)) * 16 + (n & 15)) * 8 + (k & 7);
            wb[49152 + (layer << 14) + frag] = f2bf(W_out[rel]);
        } else if (idx < 294912) {
            int rel = idx - 98304;                           // W_ff1: N=512,K=128
            int layer = rel >> 16, within = rel & 65535;
            int n = within >> 7, k = within & 127;
            int frag = ((((n >> 4) * 4 + (k >> 5)) * 4 + ((k >> 3) & 3)) * 16 + (n & 15)) * 8 + (k & 7);
            wb[98304 + (layer << 16) + frag] = f2bf(W_ff1[rel]);
        } else if (idx < 491520) {
            int rel = idx - 294912;                          // W_ff2: N=128,K=512
            int layer = rel >> 16, within = rel & 65535;
            int n = within >> 9, k = within & 511;
            int frag = ((((n >> 4) * 16 + (k >> 5)) * 4 + ((k >> 3) & 3)) * 16 + (n & 15)) * 8 + (k & 7);
            wb[294912 + (layer << 16) + frag] = f2bf(W_ff2[rel]);
        } else {
            wb[idx] = f2bf(merge_w[idx - 491520]);           // row-major (gemm_bf16 A)
        }
    } else if (idx < 705664) {
        int j = idx - 557056;
        if (j < 147456) {
            int layer = j / 49152, r = (j / 128) % 384, c = j & 127;
            float v = (r < 256) ? Woff[((size_t)layer * 256 + r) * 128 + c]
                                : Wattn[((size_t)layer * 128 + (r - 256)) * 128 + c];
            wcat[j] = f2bf(v);
        } else if (j < 148608) {
            int k = j - 147456;
            int layer = k / 384, r = k % 384;
            bcat[k] = (r < 256) ? boff[layer * 256 + r] : battn[layer * 128 + (r - 256)];
        }
    } else if (idx < 853120) {
        int j = idx - 705664;
        int cout = j / 1152, k = j % 1152;
        int tap = k >> 7, cin = k & 127;
        dconv_wb[j] = f2bf(dconv_w[(cout * 128 + cin) * 9 + tap]);
    } else if (idx < 1000576) {
        int j = idx - 853120;
        int cout = j / 1152, k = j % 1152;
        int tap = k >> 7, cin = k & 127;
        uconv_wb[j] = f2bf(uconv_w[(cout * 128 + cin) * 9 + tap]);
    } else if (idx < 1083008) {
        int j = idx - 1000576;                 // < 4*644*32
        int c4 = (j & 31) << 2;
        int tt = j >> 5;
        int p = tt % 644, n = tt / 644;
        int y, xx;
        if (p < 242)      { y = 0;       xx = p;       }
        else if (p < 484) { y = 81;      xx = p - 242; }
        else if (p < 564) { y = p - 483; xx = 0;       }
        else              { y = p - 563; xx = 241;     }
        ushort4 z = {0, 0, 0, 0};
        *(ushort4*)(xp + (((size_t)(n * 82 + y)) * 242 + xx) * 128 + c4) = z;
    } else if (idx < 1093248) {
        int j = idx - 1083008;                 // < 10240: pos tables
        int cc = j & 63;
        float expo = (float)(cc & ~1) * (1.0f / 64.0f);
        float dim_t = __expf(expo * 9.2103403719761836f);   // 10000^expo
        if (j < 2560) {
            int hh = j >> 6;
            float e = (float)(hh + 1) / (40.0f + 1e-6f) * 6.283185307179586f;
            float p = e / dim_t;
            ty[j] = (cc & 1) ? __cosf(p) : __sinf(p);
        } else {
            int j2 = j - 2560;
            int wx = j2 >> 6;
            float e = (float)(wx + 1) / (120.0f + 1e-6f) * 6.283185307179586f;
            float p = e / dim_t;
            tx[j2] = (cc & 1) ? __cosf(p) : __sinf(p);
        }
    }
}

__device__ inline void fma8(float* acc, float w, uint4 v)
{
    acc[0] = fmaf(w, __uint_as_float(v.x << 16),          acc[0]);
    acc[1] = fmaf(w, __uint_as_float(v.x & 0xffff0000u),  acc[1]);
    acc[2] = fmaf(w, __uint_as_float(v.y << 16),          acc[2]);
    acc[3] = fmaf(w, __uint_as_float(v.y & 0xffff0000u),  acc[3]);
    acc[4] = fmaf(w, __uint_as_float(v.z << 16),          acc[4]);
    acc[5] = fmaf(w, __uint_as_float(v.z & 0xffff0000u),  acc[5]);
    acc[6] = fmaf(w, __uint_as_float(v.w << 16),          acc[6]);
    acc[7] = fmaf(w, __uint_as_float(v.w & 0xffff0000u),  acc[7]);
}
__device__ inline unsigned int pk2(float a, float b)
{ return (unsigned int)f2bf(a) | ((unsigned int)f2bf(b) << 16); }

// ---------------------------------------------------------------------------
// MS deformable attention sampling. Grid 1200 (1-D): head = blockIdx.x & 7 so
// all 150 blocks of head h land on XCD h (round-robin %8 dispatch) -> the
// 614 KB per-head val slice is L2-resident on its XCD.
// Thread = (query, channel-half).
// ---------------------------------------------------------------------------
__global__ __launch_bounds__(256) void deform_sample(
    const unsigned short* __restrict__ val, const _Float16* __restrict__ off,
    const _Float16* __restrict__ attn, unsigned short* __restrict__ out)
{
    int t = threadIdx.x;
    int bid = blockIdx.x;
    int h = bid & 7;
    int q = (bid >> 3) * 128 + (t >> 1);
    int half = t & 1;
    int pix = q % HWp;
    int qy = pix / WW, qx = pix % WW;
    const _Float16* offp = off + (size_t)q * 256 + h * 32;
    const _Float16* ap   = attn + (size_t)q * 128 + h * 16;
    h16x8 ovv[4];
    ovv[0] = *(const h16x8*)(offp);
    ovv[1] = *(const h16x8*)(offp + 8);
    ovv[2] = *(const h16x8*)(offp + 16);
    ovv[3] = *(const h16x8*)(offp + 24);
    h16x8 avv[2];
    avv[0] = *(const h16x8*)(ap);
    avv[1] = *(const h16x8*)(ap + 8);
    const unsigned short* vh = val + half * 8;
    float acc[8] = {};
    #pragma unroll
    for (int l = 0; l < 4; l++) {
        const unsigned short* vb = vh + (size_t)(l * 8 + h) * (HWp * 16);
        #pragma unroll
        for (int p = 0; p < 4; p++) {
            float ox = (float)ovv[l][2 * p];
            float oy = (float)ovv[l][2 * p + 1];
            int ai = l * 4 + p;
            float a = (float)avv[ai >> 3][ai & 7];
            float x = (float)qx + ox;
            float y = (float)qy + oy;
            float xf = floorf(x), yf = floorf(y);
            int x0 = (int)xf, y0 = (int)yf;
            float wx1 = x - xf, wy1 = y - yf;
            float wx0 = 1.f - wx1, wy0 = 1.f - wy1;
            #pragma unroll
            for (int dy = 0; dy < 2; dy++) {
                int yc = y0 + dy;
                bool vy = (unsigned)yc < (unsigned)HH;
                int yci = min(max(yc, 0), HH - 1);
                float wyv = dy ? wy1 : wy0;
                #pragma unroll
                for (int dx = 0; dx < 2; dx++) {
                    int xc = x0 + dx;
                    bool vld = vy && ((unsigned)xc < (unsigned)WW);
                    int xci = min(max(xc, 0), WW - 1);
                    float wgt = vld ? a * wyv * (dx ? wx1 : wx0) : 0.f;
                    uint4 v = *(const uint4*)(vb + (size_t)(yci * WW + xci) * 16);
                    fma8(acc, wgt, v);
                }
            }
        }
    }
    uint4 o = { pk2(acc[0], acc[1]), pk2(acc[2], acc[3]),
                pk2(acc[4], acc[5]), pk2(acc[6], acc[7]) };
    *(uint4*)(out + (size_t)q * CCh + h * 16 + half * 8) = o;
}

// Bilinear 2x upsample -> padded NHWC bf16 (82,242,128), halo zeroed
__global__ void upsample_nhwc(const float* __restrict__ m, unsigned short* __restrict__ up)
{
    unsigned idx = blockIdx.x * 256u + threadIdx.x;   // < 82*242*32
    if (idx >= 82u * 242u * 32u) return;
    int c4 = (idx & 31) << 2;
    int p = idx >> 5;
    int px = p % 242, py = p / 242;
    ushort4 o = {0, 0, 0, 0};
    if (py >= 1 && py <= RHs && px >= 1 && px <= RWs) {
        int y = py - 1, x = px - 1;
        float fy = (y + 0.5f) * 0.5f - 0.5f;
        float fx = (x + 0.5f) * 0.5f - 0.5f;
        float fyf = floorf(fy), fxf = floorf(fx);
        int y0 = (int)fyf, x0 = (int)fxf;
        float wy = fy - fyf, wx = fx - fxf;
        int y0c = max(y0, 0), y1c = min(y0 + 1, HH - 1);
        int x0c = max(x0, 0), x1c = min(x0 + 1, WW - 1);
        unsigned short r[4];
        #pragma unroll
        for (int cc = 0; cc < 4; cc++) {
            const float* mp = m + (size_t)(c4 + cc) * HWp;
            float v00 = mp[y0c * WW + x0c], v01 = mp[y0c * WW + x1c];
            float v10 = mp[y1c * WW + x0c], v11 = mp[y1c * WW + x1c];
            float v = (1.f - wy) * ((1.f - wx) * v00 + wx * v01)
                    + wy * ((1.f - wx) * v10 + wx * v11);
            r[cc] = f2bf(v);
        }
        o.x = r[0]; o.y = r[1]; o.z = r[2]; o.w = r[3];
    }
    *(ushort4*)(up + (size_t)p * 128 + c4) = o;
}

// ---------------------------------------------------------------------------
extern "C" void kernel_launch(void* const* d_in, const int* in_sizes, int n_in,
                              void* d_out, int out_size, void* d_ws, size_t ws_size,
                              hipStream_t stream)
{
    const float* x       = (const float*)d_in[0];
    const float* dconv_w = (const float*)d_in[1];
    const float* dconv_b = (const float*)d_in[2];
    const float* lvl_emb = (const float*)d_in[3];
    const float* W_off   = (const float*)d_in[4];
    const float* b_off   = (const float*)d_in[5];
    const float* W_attn  = (const float*)d_in[6];
    const float* b_attn  = (const float*)d_in[7];
    const float* W_val   = (const float*)d_in[8];
    const float* b_val   = (const float*)d_in[9];
    const float* W_out   = (const float*)d_in[10];
    const float* b_out   = (const float*)d_in[11];
    const float* ln1_g   = (const float*)d_in[12];
    const float* ln1_b   = (const float*)d_in[13];
    const float* W_ff1   = (const float*)d_in[14];
    const float* b_ff1   = (const float*)d_in[15];
    const float* W_ff2   = (const float*)d_in[16];
    const float* b_ff2   = (const float*)d_in[17];
    const float* ln2_g   = (const float*)d_in[18];
    const float* ln2_b   = (const float*)d_in[19];
    const float* merge_w = (const float*)d_in[20];
    const float* merge_b = (const float*)d_in[21];
    const float* uconv_w = (const float*)d_in[22];
    const float* uconv_b = (const float*)d_in[23];

    char* wsb = (char*)d_ws;
    unsigned short* xp       = (unsigned short*)(wsb);               // 20,320,256 B (4,82,242,128)
    unsigned short* up       = (unsigned short*)(wsb + 20320256);    //  5,080,064 B (82,242,128)
    float*          src      = (float*)(wsb + 25400320);             //  9,830,400 B
    unsigned short* srcb     = (unsigned short*)(wsb + 35230720);    //  4,915,200 B
    float*          ty       = (float*)(wsb + 40145920);             //     10,240 B (40x64)
    float*          tx       = (float*)(wsb + 40156160);             //     30,720 B (120x64)
    unsigned short* qb       = (unsigned short*)(wsb + 49976320);    //  4,915,200 B
    unsigned short* valb     = (unsigned short*)(wsb + 54891520);    //  4,915,200 B
    _Float16*       attnh    = (_Float16*)(wsb + 59806720);          //  4,915,200 B
    unsigned short* attnoutb = (unsigned short*)(wsb + 69637120);    //  4,915,200 B
    unsigned short* wb       = (unsigned short*)(wsb + 104043520);   //  1,114,112 B
    unsigned short* dconv_wb = (unsigned short*)(wsb + 105452544);   //    294,912 B
    unsigned short* uconv_wb = (unsigned short*)(wsb + 105747456);   //    294,912 B
    unsigned short* wcat     = (unsigned short*)(wsb + 106042368);   //    294,912 B
    float*          bcat     = (float*)(wsb + 106337280);            //      4,608 B (end 106,341,888)
    // aliases (lifetimes disjoint):
    _Float16*       offh     = (_Float16*)xp;    // layers: xp dead after dconv gemm
    unsigned short* merge_in = up;               // written by layer-2 attn_ff; consumed before upsample writes up
    float*          mbuf     = (float*)valb;     // after layers
    float* outp = (float*)d_out;

    // bf16 linear weight table offsets (elements)
    unsigned short* W_val_b  = wb;
    unsigned short* W_out_b  = wb + 49152;
    unsigned short* W_ff1_b  = wb + 98304;
    unsigned short* W_ff2_b  = wb + 294912;
    unsigned short* merge_wb = wb + 491520;

    // 0) one-dispatch prep: weights, halo, pos tables, input transpose
    prep_all<<<5551, 256, 0, stream>>>(
        W_val, W_out, W_ff1, W_ff2, merge_w, W_off, b_off, W_attn, b_attn,
        dconv_w, uconv_w, x,
        wb, wcat, bcat, dconv_wb, uconv_wb, xp, ty, tx);

    // 1) downsample conv (implicit GEMM) -> src fp32 + srcb bf16 + qb, relu
    conv3x3_gemm<0><<<dim3(2, 300), 256, 0, stream>>>(
        xp, dconv_wb, dconv_b, src, srcb, ty, tx, lvl_emb, qb);

    // 2) encoder layers (3 dispatches each)
    for (int i = 0; i < 3; i++) {
        gemm_oav<<<dim3(8, 300), 256, 0, stream>>>(
            qb, srcb,
            wcat + (size_t)i * 49152, bcat + i * 384,
            W_val_b + (size_t)i * 16384, b_val + i * 128,
            offh, attnh, valb);
        deform_sample<<<1200, 256, 0, stream>>>(valb, offh, attnh, attnoutb);
        if (i < 2) {
            attn_ff<true, false><<<600, 256, 0, stream>>>(
                attnoutb, src,
                W_out_b + (size_t)i * 16384, b_out + i * 128,
                ln1_g + i * 128, ln1_b + i * 128,
                W_ff1_b + (size_t)i * 65536, b_ff1 + i * 512,
                W_ff2_b + (size_t)i * 65536, b_ff2 + i * 128,
                ln2_g + i * 128, ln2_b + i * 128,
                src, srcb, ty, tx, lvl_emb, qb, nullptr);
        } else {
            attn_ff<false, true><<<600, 256, 0, stream>>>(
                attnoutb, src,
                W_out_b + (size_t)i * 16384, b_out + i * 128,
                ln1_g + i * 128, ln1_b + i * 128,
                W_ff1_b + (size_t)i * 65536, b_ff1 + i * 512,
                W_ff2_b + (size_t)i * 65536, b_ff2 + i * 128,
                ln2_g + i * 128, ln2_b + i * 128,
                nullptr, nullptr, nullptr, nullptr, nullptr, nullptr, merge_in);
        }
    }

    // 3) merge 1x1 conv, weights-as-A trick: mbuf[128,4800], BM=64 (150 blocks)
    gemm_bf16<true, true, 0, 64><<<dim3(75, 2), 256, 0, stream>>>(
        merge_wb, merge_in, merge_b, mbuf, nullptr, 128, 4800, 512);

    // 4) bilinear 2x upsample -> padded NHWC bf16
    upsample_nhwc<<<2482, 256, 0, stream>>>(mbuf, up);

    // 5) uconv (implicit GEMM, transposed store) -> d_out (128,19200), relu
    conv3x3_gemm<1><<<dim3(2, 300), 256, 0, stream>>>(
        up, uconv_wb, uconv_b, outp, nullptr, nullptr, nullptr, nullptr, nullptr);
}

// Round 12
// 419.561 us; speedup vs baseline: 1.0104x; 1.0104x over previous
//
#include <hip/hip_runtime.h>
#include <math.h>
#include <cstddef>

// Problem constants
#define LQ   19200          // NL*H*W tokens
#define HH   40
#define WW   120
#define HWp  4800
#define CCh  128
#define NHd  8
#define NLv  4
#define NPt  4
#define RHs  80
#define RWs  240

typedef __attribute__((ext_vector_type(8))) short bf16x8;
typedef __attribute__((ext_vector_type(4))) float f32x4;
typedef __attribute__((ext_vector_type(8))) _Float16 h16x8;
typedef __attribute__((address_space(1))) const unsigned int GUI;
typedef __attribute__((address_space(3))) unsigned int LUI;

__device__ inline unsigned short f2bf(float f) {
    unsigned int u = __float_as_uint(f);
    u += 0x7fffu + ((u >> 16) & 1u);        // round-to-nearest-even
    return (unsigned short)(u >> 16);
}
__device__ inline float bf2f(unsigned int lo16) { return __uint_as_float(lo16 << 16); }

// sine pos-embed from small tables: pos(row, col) = tab + lvl_emb
__device__ inline float pos_eval(const float* __restrict__ ty,
                                 const float* __restrict__ tx,
                                 const float* __restrict__ lvl,
                                 int row, int col)
{
    int n = row / HWp, pix = row % HWp;
    int hh = pix / WW, wx = pix % WW;
    float t = (col < 64) ? ty[hh * 64 + col] : tx[wx * 64 + (col - 64)];
    return t + lvl[n * CCh + col];
}

// ---------------------------------------------------------------------------
// bf16 MFMA GEMM: Out[M,N] = A[M,K] @ Bw[N,K]^T + bias, opt relu.
// Double-buffered LDS K-loop. BMD ∈ {64,128}: block-M tile (64 doubles the
// grid for small GEMMs — latency hiding by block count).
// BIAS_ROW: bias indexed by row (weights-as-A transposed trick).
// OMODE: 0 = fp32 OutF; 1 = bf16 OutB; 2 = both.
// ---------------------------------------------------------------------------
template<bool BIAS_ROW, bool RELU, int OMODE, int BMD>
__global__ __launch_bounds__(256) void gemm_bf16(
    const unsigned short* __restrict__ A,
    const unsigned short* __restrict__ Bw,
    const float* __restrict__ bias,
    float* __restrict__ OutF, unsigned short* __restrict__ OutB,
    int M, int N, int K)
{
    constexpr int BN = 64, BK = 32;
    constexpr int MI = BMD / 32;                 // row-tiles per wave
    __shared__ unsigned short As[2][BMD * BK];   // row-major [m][k]
    __shared__ unsigned short Bs[2][BN * BK];
    const int bm = blockIdx.y * BMD, bn = blockIdx.x * BN;
    const int tid = threadIdx.x;
    const int wid = tid >> 6, lane = tid & 63;
    const int wm = (wid & 1) * (BMD / 2), wn = (wid >> 1) * 32;
    const int lm = lane & 15, lqd = lane >> 4;

    f32x4 acc[MI][2] = {};

    const int arow = lane >> 2;          // 0..15 within a 16-row chunk
    const int akc  = (lane & 3) * 8;     // k element offset (16 B granules)
    const unsigned short* aG0;
    const unsigned short* aG1 = nullptr;
    if constexpr (BMD == 128) {
        aG0 = A + (size_t)(bm + wid * 32 +      arow) * K + akc;
        aG1 = A + (size_t)(bm + wid * 32 + 16 + arow) * K + akc;
    } else {
        aG0 = A + (size_t)(bm + wid * 16 + arow) * K + akc;
    }
    const unsigned short* bG = Bw + (size_t)(bn + wid * 16 + arow) * K + akc;
    const int aoff = (BMD == 128) ? (wid * 1024 + lane * 8) : (wid * 512 + lane * 8);
    const int boff = wid * 512 + lane * 8;

    auto stage = [&](int b, int k0) {
        __builtin_amdgcn_global_load_lds((GUI*)(aG0 + k0), (LUI*)(As[b] + aoff), 16, 0, 0);
        if constexpr (BMD == 128)
            __builtin_amdgcn_global_load_lds((GUI*)(aG1 + k0), (LUI*)(As[b] + aoff + 512), 16, 0, 0);
        __builtin_amdgcn_global_load_lds((GUI*)(bG + k0), (LUI*)(Bs[b] + boff), 16, 0, 0);
    };

    stage(0, 0);
    __syncthreads();
    int buf = 0;
    for (int k0 = 0; k0 < K; k0 += BK, buf ^= 1) {
        if (k0 + BK < K) stage(buf ^ 1, k0 + BK);
        bf16x8 a[MI], b[2];
        #pragma unroll
        for (int i = 0; i < MI; i++)
            a[i] = *(const bf16x8*)(As[buf] + (wm + i * 16 + lm) * BK + lqd * 8);
        #pragma unroll
        for (int j = 0; j < 2; j++)
            b[j] = *(const bf16x8*)(Bs[buf] + (wn + j * 16 + lm) * BK + lqd * 8);
        #pragma unroll
        for (int i = 0; i < MI; i++)
            #pragma unroll
            for (int j = 0; j < 2; j++)
                acc[i][j] = __builtin_amdgcn_mfma_f32_16x16x32_bf16(a[i], b[j], acc[i][j], 0, 0, 0);
        __syncthreads();
    }

    #pragma unroll
    for (int i = 0; i < MI; i++) {
        int row0 = bm + wm + i * 16 + lqd * 4;
        #pragma unroll
        for (int j = 0; j < 2; j++) {
            int col = bn + wn + j * 16 + lm;
            float bc = BIAS_ROW ? 0.f : bias[col];
            #pragma unroll
            for (int r = 0; r < 4; r++) {
                int row = row0 + r;
                float v = acc[i][j][r] + (BIAS_ROW ? bias[row] : bc);
                if (RELU) v = fmaxf(v, 0.f);
                size_t o = (size_t)row * N + col;
                if (OMODE == 0) OutF[o] = v;
                else if (OMODE == 1) OutB[o] = f2bf(v);
                else { OutF[o] = v; OutB[o] = f2bf(v); }
            }
        }
    }
}

// ---------------------------------------------------------------------------
// Merged off/attn + val GEMM for one layer. Grid dim3(8, 300), BM=64, K=128.
// Double-buffered LDS. BM=64 doubles blocks (1200->2400) at identical global
// traffic — these small GEMMs are latency-hidden by block count (R8 lesson).
// bx<6: A=qb, W=Woa(384x128): col<256 -> fp16 off (stride 256);
//       col>=256 -> softmax16 -> fp16 attn (stride 128).
// bx>=6: A=srcb, W=Wv(128x128): bf16 val in plane layout [l][h][4800][16].
// ---------------------------------------------------------------------------
__global__ __launch_bounds__(256) void gemm_oav(
    const unsigned short* __restrict__ Aq,
    const unsigned short* __restrict__ Asrc,
    const unsigned short* __restrict__ Woa, const float* __restrict__ boa,
    const unsigned short* __restrict__ Wv,  const float* __restrict__ bv,
    _Float16* __restrict__ OutH, _Float16* __restrict__ OutH2,
    unsigned short* __restrict__ OutV)
{
    constexpr int BK = 32, K = 128;
    __shared__ unsigned short As[2][64 * BK];
    __shared__ unsigned short Bs[2][64 * BK];
    const int bx = blockIdx.x;
    const bool isv = bx >= 6;
    const unsigned short* A  = isv ? Asrc : Aq;
    const unsigned short* Bw = isv ? Wv : Woa;
    const float* bias = isv ? bv : boa;
    const int bn = isv ? (bx - 6) * 64 : bx * 64;
    const int bm = blockIdx.y * 64;
    const int tid = threadIdx.x;
    const int wid = tid >> 6, lane = tid & 63;
    const int wm = (wid & 1) * 32, wn = (wid >> 1) * 32;
    const int lm = lane & 15, lqd = lane >> 4;

    f32x4 acc[2][2] = {};

    const int arow = lane >> 2;
    const int akc  = (lane & 3) * 8;
    const unsigned short* aG = A  + (size_t)(bm + wid * 16 + arow) * K + akc;
    const unsigned short* bG = Bw + (size_t)(bn + wid * 16 + arow) * K + akc;
    const int loff = wid * 512 + lane * 8;

    auto stage = [&](int b, int k0) {
        __builtin_amdgcn_global_load_lds((GUI*)(aG + k0), (LUI*)(As[b] + loff), 16, 0, 0);
        __builtin_amdgcn_global_load_lds((GUI*)(bG + k0), (LUI*)(Bs[b] + loff), 16, 0, 0);
    };

    stage(0, 0);
    __syncthreads();
    int buf = 0;
    for (int k0 = 0; k0 < K; k0 += BK, buf ^= 1) {
        if (k0 + BK < K) stage(buf ^ 1, k0 + BK);
        bf16x8 a[2], b[2];
        #pragma unroll
        for (int i = 0; i < 2; i++)
            a[i] = *(const bf16x8*)(As[buf] + (wm + i * 16 + lm) * BK + lqd * 8);
        #pragma unroll
        for (int j = 0; j < 2; j++)
            b[j] = *(const bf16x8*)(Bs[buf] + (wn + j * 16 + lm) * BK + lqd * 8);
        #pragma unroll
        for (int i = 0; i < 2; i++)
            #pragma unroll
            for (int j = 0; j < 2; j++)
                acc[i][j] = __builtin_amdgcn_mfma_f32_16x16x32_bf16(a[i], b[j], acc[i][j], 0, 0, 0);
        __syncthreads();
    }

    #pragma unroll
    for (int i = 0; i < 2; i++) {
        int row0 = bm + wm + i * 16 + lqd * 4;
        #pragma unroll
        for (int j = 0; j < 2; j++) {
            int col = bn + wn + j * 16 + lm;
            float bc = bias[col];
            if (!isv) {
                if (col < 256) {
                    #pragma unroll
                    for (int r = 0; r < 4; r++)
                        OutH[(size_t)(row0 + r) * 256 + col] = (_Float16)(acc[i][j][r] + bc);
                } else {
                    #pragma unroll
                    for (int r = 0; r < 4; r++) {
                        float v = acc[i][j][r] + bc;
                        float m = v;
                        #pragma unroll
                        for (int msk = 1; msk < 16; msk <<= 1)
                            m = fmaxf(m, __shfl_xor(m, msk));
                        float e = __expf(v - m);
                        float s = e;
                        #pragma unroll
                        for (int msk = 1; msk < 16; msk <<= 1)
                            s += __shfl_xor(s, msk);
                        OutH2[(size_t)(row0 + r) * 128 + (col - 256)] = (_Float16)(e / s);
                    }
                }
            } else {
                #pragma unroll
                for (int r = 0; r < 4; r++) {
                    int row = row0 + r;
                    int plane = (row / HWp) * 8 + (col >> 4);
                    size_t o = ((size_t)plane * HWp + (row % HWp)) * 16 + (col & 15);
                    OutV[o] = f2bf(acc[i][j][r] + bc);
                }
            }
        }
    }
}

// ---------------------------------------------------------------------------
// Fully-fused post-attention block, 16 tokens/block (4 waves, grid 1200 —
// 2x the blocks of the 32-token variant; same lever that paid on conv/oav:
// latency hiding by block count; weight L2 traffic doubles but is ~5 us).
// Weights Wout/Wff1/Wff2 in MFMA FRAGMENT LAYOUT [n0][kc][lqd][lm][8].
//   delta1 = attnout @ W_out^T + b_out
//   y1 = LayerNorm(src + delta1) * g1 + c1
//   for qc in 0..3: f = relu(y1 @ Wff1[qc]^T + b); delta2 += f @ Wff2[:,qc]^T
//   y2 = LayerNorm(y1 + delta2 + bff2) * g2 + c2
// WQ: also write qb = bf16(y2 + pos(row,col)) from ty/tx/lvl tables.
// WMERGE: write only merge-layout bf16 mergeb[pix][n*128+c] (final layer).
// ---------------------------------------------------------------------------
template<bool WQ, bool WMERGE>
__global__ __launch_bounds__(256) void attn_ff(
    const unsigned short* __restrict__ attnout, const float* __restrict__ srcF_in,
    const unsigned short* __restrict__ Wout, const float* __restrict__ bout,
    const float* __restrict__ g1, const float* __restrict__ c1,
    const unsigned short* __restrict__ Wff1, const float* __restrict__ bff1,
    const unsigned short* __restrict__ Wff2, const float* __restrict__ bff2,
    const float* __restrict__ g2, const float* __restrict__ c2,
    float* __restrict__ outF, unsigned short* __restrict__ outB,
    const float* __restrict__ ty, const float* __restrict__ tx,
    const float* __restrict__ lvl, unsigned short* __restrict__ qb,
    unsigned short* __restrict__ mergeb)
{
    __shared__ unsigned short fs[16 * 136];     //  4,352 B ff activation chunk
    __shared__ unsigned short y1s[16 * 136];    //  4,352 B LN1 output (bf16)
    __shared__ float red[4][2][16];             //    512 B cross-wave LN partials
    const int bm = blockIdx.x * 16;
    const int tid = threadIdx.x;
    const int wid = tid >> 6, lane = tid & 63;
    const int lm = lane & 15, lqd = lane >> 4;
    const int wn2 = wid * 32;                   // col ownership, phases A & C

    // ---- Phase A: delta1 = attnout @ Wout^T (cols wn2..wn2+32)
    float y1r[2][4];
    {
        f32x4 accA[2] = {};
        for (int k0 = 0; k0 < 128; k0 += 32) {
            int kc = k0 >> 5;
            bf16x8 a = *(const bf16x8*)(attnout + (size_t)(bm + lm) * 128 + k0 + lqd * 8);
            #pragma unroll
            for (int j = 0; j < 2; j++) {
                bf16x8 b = *(const bf16x8*)(Wout + ((size_t)((wid * 2 + j) * 4 + kc) * 64 + lane) * 8);
                accA[j] = __builtin_amdgcn_mfma_f32_16x16x32_bf16(a, b, accA[j], 0, 0, 0);
            }
        }
        #pragma unroll
        for (int j = 0; j < 2; j++) {
            int col = wn2 + j * 16 + lm;
            float bc = bout[col];
            #pragma unroll
            for (int r = 0; r < 4; r++) {
                int row = bm + lqd * 4 + r;
                y1r[j][r] = accA[j][r] + bc + srcF_in[(size_t)row * 128 + col];
            }
        }
    }
    // LN1 stats (rows bm + lqd*4 + r, reduce over 128 cols = 16 lanes x 2 j x 4 waves)
    #pragma unroll
    for (int r = 0; r < 4; r++) {
        float s = y1r[0][r] + y1r[1][r];
        float q = y1r[0][r] * y1r[0][r] + y1r[1][r] * y1r[1][r];
        #pragma unroll
        for (int msk = 1; msk < 16; msk <<= 1) {
            s += __shfl_xor(s, msk);
            q += __shfl_xor(q, msk);
        }
        if (lm == 0) {
            int rl = lqd * 4 + r;
            red[wid][0][rl] = s;
            red[wid][1][rl] = q;
        }
    }
    __syncthreads();
    {
        float mean[4], inv[4];
        #pragma unroll
        for (int r = 0; r < 4; r++) {
            int rl = lqd * 4 + r;
            float s = red[0][0][rl] + red[1][0][rl] + red[2][0][rl] + red[3][0][rl];
            float q = red[0][1][rl] + red[1][1][rl] + red[2][1][rl] + red[3][1][rl];
            float m = s * (1.0f / 128.0f);
            float v = q * (1.0f / 128.0f) - m * m;
            mean[r] = m;
            inv[r] = rsqrtf(v + 1e-5f);
        }
        #pragma unroll
        for (int j = 0; j < 2; j++) {
            int col = wn2 + j * 16 + lm;
            float gc = g1[col], bc = c1[col];
            #pragma unroll
            for (int r = 0; r < 4; r++) {
                float y = (y1r[j][r] - mean[r]) * inv[r] * gc + bc;
                y1r[j][r] = y;
                y1s[(lqd * 4 + r) * 136 + col] = f2bf(y);
            }
        }
    }
    __syncthreads();

    // ---- Phases B+C, chunked over ff dim (4 chunks of 128)
    f32x4 acc2[2] = {};
    for (int qc = 0; qc < 4; qc++) {
        // Phase B chunk: f = relu(y1 @ Wff1[qc*128 + wid*32 ..]^T + b)
        {
            f32x4 accB[2] = {};
            for (int k0 = 0; k0 < 128; k0 += 32) {
                int kc = k0 >> 5;
                bf16x8 a = *(const bf16x8*)(y1s + lm * 136 + k0 + lqd * 8);
                #pragma unroll
                for (int j = 0; j < 2; j++) {
                    bf16x8 b = *(const bf16x8*)(Wff1 + ((size_t)((qc * 8 + wid * 2 + j) * 4 + kc) * 64 + lane) * 8);
                    accB[j] = __builtin_amdgcn_mfma_f32_16x16x32_bf16(a, b, accB[j], 0, 0, 0);
                }
            }
            #pragma unroll
            for (int j = 0; j < 2; j++) {
                int col = wid * 32 + j * 16 + lm;            // 0..127 within chunk
                float bc = bff1[qc * 128 + col];
                #pragma unroll
                for (int r = 0; r < 4; r++) {
                    int row = lqd * 4 + r;
                    fs[row * 136 + col] = f2bf(fmaxf(accB[j][r] + bc, 0.f));
                }
            }
        }
        __syncthreads();
        // Phase C chunk: acc2 += f @ Wff2[wn2.., qc*128..]^T
        for (int k0 = 0; k0 < 128; k0 += 32) {
            int kc = qc * 4 + (k0 >> 5);       // global k-chunk in K=512
            bf16x8 a = *(const bf16x8*)(fs + lm * 136 + k0 + lqd * 8);
            #pragma unroll
            for (int j = 0; j < 2; j++) {
                bf16x8 b = *(const bf16x8*)(Wff2 + ((size_t)((wid * 2 + j) * 16 + kc) * 64 + lane) * 8);
                acc2[j] = __builtin_amdgcn_mfma_f32_16x16x32_bf16(a, b, acc2[j], 0, 0, 0);
            }
        }
        __syncthreads();   // fs dead; next chunk may overwrite
    }

    // z2 = delta2 + bias + y1 (registers), LN2
    float z[2][4];
    #pragma unroll
    for (int j = 0; j < 2; j++) {
        int col = wn2 + j * 16 + lm;
        float bc = bff2[col];
        #pragma unroll
        for (int r = 0; r < 4; r++)
            z[j][r] = acc2[j][r] + bc + y1r[j][r];
    }
    #pragma unroll
    for (int r = 0; r < 4; r++) {
        float s = z[0][r] + z[1][r];
        float q = z[0][r] * z[0][r] + z[1][r] * z[1][r];
        #pragma unroll
        for (int msk = 1; msk < 16; msk <<= 1) {
            s += __shfl_xor(s, msk);
            q += __shfl_xor(q, msk);
        }
        if (lm == 0) {
            int rl = lqd * 4 + r;
            red[wid][0][rl] = s;
            red[wid][1][rl] = q;
        }
    }
    __syncthreads();

    {
        float mean[4], inv[4];
        #pragma unroll
        for (int r = 0; r < 4; r++) {
            int rl = lqd * 4 + r;
            float s = red[0][0][rl] + red[1][0][rl] + red[2][0][rl] + red[3][0][rl];
            float q = red[0][1][rl] + red[1][1][rl] + red[2][1][rl] + red[3][1][rl];
            float m = s * (1.0f / 128.0f);
            float v = q * (1.0f / 128.0f) - m * m;
            mean[r] = m;
            inv[r] = rsqrtf(v + 1e-5f);
        }
        #pragma unroll
        for (int j = 0; j < 2; j++) {
            int col = wn2 + j * 16 + lm;
            float gc = g2[col], bc2 = c2[col];
            #pragma unroll
            for (int r = 0; r < 4; r++) {
                int row = bm + lqd * 4 + r;
                float y = (z[j][r] - mean[r]) * inv[r] * gc + bc2;
                if constexpr (WMERGE) {
                    int n = row / HWp, pix = row % HWp;
                    mergeb[(size_t)pix * 512 + n * 128 + col] = f2bf(y);
                } else {
                    size_t o = (size_t)row * 128 + col;
                    outF[o] = y;
                    outB[o] = f2bf(y);
                    if constexpr (WQ)
                        qb[o] = f2bf(y + pos_eval(ty, tx, lvl, row, col));
                }
            }
        }
    }
}

// ---------------------------------------------------------------------------
// Implicit-GEMM 3x3 conv from padded NHWC bf16 input, tap-major weights.
// BM=64 (grid 2x300 = 600 blocks). Double-buffered LDS chunk loop.
// MODE 0: dconv  — X:(4,82,242,128), stride 2, out: src fp32 + srcb bf16 +
//                  qb = bf16(src+pos(tables)), relu.
// MODE 1: uconv  — X:(82,242,128), stride 1, out: d_out fp32 (128,19200)
//                  via LDS-transposed store, relu.
// ---------------------------------------------------------------------------
template<int MODE>
__global__ __launch_bounds__(256) void conv3x3_gemm(
    const unsigned short* __restrict__ X,
    const unsigned short* __restrict__ Wp,
    const float* __restrict__ bias,
    float* __restrict__ OutF, unsigned short* __restrict__ OutB,
    const float* __restrict__ ty, const float* __restrict__ tx,
    const float* __restrict__ lvl, unsigned short* __restrict__ Qb)
{
    constexpr int BM = 64, BN = 64, BK = 32;
    constexpr int SMEM = (MODE == 1) ? 17408 : 16384;   // dbuf A/B = 16 KB; Ts = 17,408 B
    __shared__ __align__(16) unsigned char smem[SMEM];
    unsigned short* As = (unsigned short*)smem;            // [2][64*32]
    unsigned short* Bs = (unsigned short*)(smem + 8192);   // [2][64*32]
    const int bm = blockIdx.y * BM, bn = blockIdx.x * BN;
    const int tid = threadIdx.x;
    const int wid = tid >> 6, lane = tid & 63;
    const int wm = (wid & 1) * 32, wn = (wid >> 1) * 32;
    const int lm = lane & 15, lqd = lane >> 4;

    f32x4 acc[2][2] = {};

    const int arow = lane >> 2;
    const int akc  = (lane & 3) * 8;
    const int r0 = bm + wid * 16 + arow;
    size_t bA0;
    if (MODE == 0) {
        int n0 = r0 / HWp, rem0 = r0 % HWp, oh0 = rem0 / WW, ow0 = rem0 % WW;
        bA0 = ((size_t)(n0 * 82 + oh0 * 2) * 242 + ow0 * 2) * 128;
    } else {
        int y0 = r0 / RWs, x0 = r0 % RWs;
        bA0 = ((size_t)y0 * 242 + x0) * 128;
    }
    const unsigned short* bG = Wp + (size_t)(bn + wid * 16 + arow) * 1152 + akc;
    const int loff = wid * 512 + lane * 8;

    auto stage = [&](int b, int c) {
        int tap = c >> 2;
        int cpart = (c & 3) << 5;
        int ky = tap / 3, kx = tap % 3;
        int toff = (ky * 242 + kx) * 128 + cpart + akc;
        __builtin_amdgcn_global_load_lds((GUI*)(X + bA0 + toff), (LUI*)(As + b * 2048 + loff), 16, 0, 0);
        __builtin_amdgcn_global_load_lds((GUI*)(bG + c * 32), (LUI*)(Bs + b * 2048 + loff), 16, 0, 0);
    };

    stage(0, 0);
    __syncthreads();
    int buf = 0;
    for (int chunk = 0; chunk < 36; chunk++, buf ^= 1) {
        if (chunk < 35) stage(buf ^ 1, chunk + 1);
        bf16x8 a[2], b[2];
        #pragma unroll
        for (int i = 0; i < 2; i++)
            a[i] = *(const bf16x8*)(As + buf * 2048 + (wm + i * 16 + lm) * BK + lqd * 8);
        #pragma unroll
        for (int j = 0; j < 2; j++)
            b[j] = *(const bf16x8*)(Bs + buf * 2048 + (wn + j * 16 + lm) * BK + lqd * 8);
        #pragma unroll
        for (int i = 0; i < 2; i++)
            #pragma unroll
            for (int j = 0; j < 2; j++)
                acc[i][j] = __builtin_amdgcn_mfma_f32_16x16x32_bf16(a[i], b[j], acc[i][j], 0, 0, 0);
        __syncthreads();
    }

    if (MODE == 0) {
        #pragma unroll
        for (int i = 0; i < 2; i++) {
            int row0 = bm + wm + i * 16 + lqd * 4;
            #pragma unroll
            for (int j = 0; j < 2; j++) {
                int col = bn + wn + j * 16 + lm;
                float bc = bias[col];
                #pragma unroll
                for (int r = 0; r < 4; r++) {
                    int row = row0 + r;
                    float v = fmaxf(acc[i][j][r] + bc, 0.f);
                    size_t o = (size_t)row * 128 + col;
                    OutF[o] = v;
                    OutB[o] = f2bf(v);
                    Qb[o] = f2bf(v + pos_eval(ty, tx, lvl, row, col));
                }
            }
        }
    } else {
        float* Ts = (float*)smem;                 // 64 ch x 68 pix floats
        #pragma unroll
        for (int i = 0; i < 2; i++) {
            int lr0 = wm + i * 16 + lqd * 4;
            #pragma unroll
            for (int j = 0; j < 2; j++) {
                int lc = wn + j * 16 + lm;
                float bc = bias[bn + lc];
                #pragma unroll
                for (int r = 0; r < 4; r++)
                    Ts[lc * 68 + lr0 + r] = fmaxf(acc[i][j][r] + bc, 0.f);
            }
        }
        __syncthreads();
        for (int f = tid; f < 64 * 16; f += 256) {
            int ch = f >> 4, p4 = (f & 15) << 2;
            float4 v4 = *(const float4*)(Ts + ch * 68 + p4);
            *(float4*)(OutF + (size_t)(bn + ch) * 19200 + bm + p4) = v4;
        }
    }
}

// ---------------------------------------------------------------------------
// One-dispatch prep: linear weights -> bf16 (Wout/Wff1/Wff2 in MFMA fragment
// layout [n0][kc][lqd][lm][8]), [W_off;W_attn] concat, conv weights
// tap-major, halo zero, pos sin/cos TABLES (ty 40x64, tx 120x64), and the
// NCHW->NHWC input transpose.
// ---------------------------------------------------------------------------
__global__ __launch_bounds__(256) void prep_all(
    const float* __restrict__ W_val, const float* __restrict__ W_out,
    const float* __restrict__ W_ff1, const float* __restrict__ W_ff2,
    const float* __restrict__ merge_w,
    const float* __restrict__ Woff, const float* __restrict__ boff,
    const float* __restrict__ Wattn, const float* __restrict__ battn,
    const float* __restrict__ dconv_w, const float* __restrict__ uconv_w,
    const float* __restrict__ x,
    unsigned short* __restrict__ wb, unsigned short* __restrict__ wcat,
    float* __restrict__ bcat, unsigned short* __restrict__ dconv_wb,
    unsigned short* __restrict__ uconv_wb, unsigned short* __restrict__ xp,
    float* __restrict__ ty, float* __restrict__ tx)
{
    __shared__ unsigned short t[240 * 36];       // used by transpose blocks only
    int blk = blockIdx.x;
    if (blk >= 4271) {
        // NCHW fp32 (4,128,80,240) -> padded NHWC bf16 (4,82,242,128)
        int b = blk - 4271;                      // < 1280: (n, y, 32-ch tile)
        int ct = b & 3;
        int tmp = b >> 2;
        int y = tmp % 80, n = tmp / 80;
        const float* xin = x + (((size_t)(n * 128 + ct * 32)) * 80 + y) * 240;
        for (int f = threadIdx.x; f < 32 * 240; f += 256) {
            int c = f / 240, xc = f % 240;
            t[xc * 36 + c] = f2bf(xin[(size_t)c * 19200 + xc]);
        }
        __syncthreads();
        unsigned short* out = xp + (((size_t)(n * 82 + y + 1)) * 242 + 1) * 128 + ct * 32;
        for (int f = threadIdx.x; f < 240 * 8; f += 256) {
            int xc = f >> 3, c4 = (f & 7) << 2;
            ushort4 v = *(const ushort4*)(t + xc * 36 + c4);
            *(ushort4*)(out + (size_t)xc * 128 + c4) = v;
        }
        return;
    }
    int idx = blk * 256 + threadIdx.x;
    if (idx < 557056) {
        if (idx < 49152) {
            wb[idx] = f2bf(W_val[idx]);                      // row-major (gemm_oav)
        } else if (idx < 98304) {
            int rel = idx - 49152;                           // W_out: N=128,K=128
            int layer = rel >> 14, within = rel & 16383;
            int n = within >> 7, k = within & 127;
            int frag = ((((n >> 4) * 4 + (k >> 5)) * 4 + ((k >> 3) & 3)) * 16 + (n & 15)) * 8 + (k & 7);
            wb[49152 + (layer << 14) + frag] = f2bf(W_out[rel]);
        } else if (idx < 294912) {
            int rel = idx - 98304;                           // W_ff1: N=512,K=128
            int layer = rel >> 16, within = rel & 65535;
            int n = within >> 7, k = within & 127;
            int frag = ((((n >> 4) * 4 + (k >> 5)) * 4 + ((k >> 3) & 3)) * 16 + (n & 15)) * 8 + (k & 7);
            wb[98304 + (layer << 16) + frag] = f2bf(W_ff1[rel]);
        } else if (idx < 491520) {
            int rel = idx - 294912;                          // W_ff2: N=128,K=512
            int layer = rel >> 16, within = rel & 65535;
            int n = within >> 9, k = within & 511;
            int frag = ((((n >> 4) * 16 + (k >> 5)) * 4 + ((k >> 3) & 3)) * 16 + (n & 15)) * 8 + (k & 7);
            wb[294912 + (layer << 16) + frag] = f2bf(W_ff2[rel]);
        } else {
            wb[idx] = f2bf(merge_w[idx - 491520]);           // row-major (gemm_bf16 A)
        }
    } else if (idx < 705664) {
        int j = idx - 557056;
        if (j < 147456) {
            int layer = j / 49152, r = (j / 128) % 384, c = j & 127;
            float v = (r < 256) ? Woff[((size_t)layer * 256 + r) * 128 + c]
                                : Wattn[((size_t)layer * 128 + (r - 256)) * 128 + c];
            wcat[j] = f2bf(v);
        } else if (j < 148608) {
            int k = j - 147456;
            int layer = k / 384, r = k % 384;
            bcat[k] = (r < 256) ? boff[layer * 256 + r] : battn[layer * 128 + (r - 256)];
        }
    } else if (idx < 853120) {
        int j = idx - 705664;
        int cout = j / 1152, k = j % 1152;
        int tap = k >> 7, cin = k & 127;
        dconv_wb[j] = f2bf(dconv_w[(cout * 128 + cin) * 9 + tap]);
    } else if (idx < 1000576) {
        int j = idx - 853120;
        int cout = j / 1152, k = j % 1152;
        int tap = k >> 7, cin = k & 127;
        uconv_wb[j] = f2bf(uconv_w[(cout * 128 + cin) * 9 + tap]);
    } else if (idx < 1083008) {
        int j = idx - 1000576;                 // < 4*644*32
        int c4 = (j & 31) << 2;
        int tt = j >> 5;
        int p = tt % 644, n = tt / 644;
        int y, xx;
        if (p < 242)      { y = 0;       xx = p;       }
        else if (p < 484) { y = 81;      xx = p - 242; }
        else if (p < 564) { y = p - 483; xx = 0;       }
        else              { y = p - 563; xx = 241;     }
        ushort4 z = {0, 0, 0, 0};
        *(ushort4*)(xp + (((size_t)(n * 82 + y)) * 242 + xx) * 128 + c4) = z;
    } else if (idx < 1093248) {
        int j = idx - 1083008;                 // < 10240: pos tables
        int cc = j & 63;
        float expo = (float)(cc & ~1) * (1.0f / 64.0f);
        float dim_t = __expf(expo * 9.2103403719761836f);   // 10000^expo
        if (j < 2560) {
            int hh = j >> 6;
            float e = (float)(hh + 1) / (40.0f + 1e-6f) * 6.283185307179586f;
            float p = e / dim_t;
            ty[j] = (cc & 1) ? __cosf(p) : __sinf(p);
        } else {
            int j2 = j - 2560;
            int wx = j2 >> 6;
            float e = (float)(wx + 1) / (120.0f + 1e-6f) * 6.283185307179586f;
            float p = e / dim_t;
            tx[j2] = (cc & 1) ? __cosf(p) : __sinf(p);
        }
    }
}

__device__ inline void fma8(float* acc, float w, uint4 v)
{
    acc[0] = fmaf(w, __uint_as_float(v.x << 16),          acc[0]);
    acc[1] = fmaf(w, __uint_as_float(v.x & 0xffff0000u),  acc[1]);
    acc[2] = fmaf(w, __uint_as_float(v.y << 16),          acc[2]);
    acc[3] = fmaf(w, __uint_as_float(v.y & 0xffff0000u),  acc[3]);
    acc[4] = fmaf(w, __uint_as_float(v.z << 16),          acc[4]);
    acc[5] = fmaf(w, __uint_as_float(v.z & 0xffff0000u),  acc[5]);
    acc[6] = fmaf(w, __uint_as_float(v.w << 16),          acc[6]);
    acc[7] = fmaf(w, __uint_as_float(v.w & 0xffff0000u),  acc[7]);
}
__device__ inline unsigned int pk2(float a, float b)
{ return (unsigned int)f2bf(a) | ((unsigned int)f2bf(b) << 16); }

// ---------------------------------------------------------------------------
// MS deformable attention sampling. Grid 1200 (1-D): head = blockIdx.x & 7 so
// all 150 blocks of head h land on XCD h (round-robin %8 dispatch) -> the
// 614 KB per-head val slice is L2-resident on its XCD.
// Thread = (query, channel-half).
// ---------------------------------------------------------------------------
__global__ __launch_bounds__(256) void deform_sample(
    const unsigned short* __restrict__ val, const _Float16* __restrict__ off,
    const _Float16* __restrict__ attn, unsigned short* __restrict__ out)
{
    int t = threadIdx.x;
    int bid = blockIdx.x;
    int h = bid & 7;
    int q = (bid >> 3) * 128 + (t >> 1);
    int half = t & 1;
    int pix = q % HWp;
    int qy = pix / WW, qx = pix % WW;
    const _Float16* offp = off + (size_t)q * 256 + h * 32;
    const _Float16* ap   = attn + (size_t)q * 128 + h * 16;
    h16x8 ovv[4];
    ovv[0] = *(const h16x8*)(offp);
    ovv[1] = *(const h16x8*)(offp + 8);
    ovv[2] = *(const h16x8*)(offp + 16);
    ovv[3] = *(const h16x8*)(offp + 24);
    h16x8 avv[2];
    avv[0] = *(const h16x8*)(ap);
    avv[1] = *(const h16x8*)(ap + 8);
    const unsigned short* vh = val + half * 8;
    float acc[8] = {};
    #pragma unroll
    for (int l = 0; l < 4; l++) {
        const unsigned short* vb = vh + (size_t)(l * 8 + h) * (HWp * 16);
        #pragma unroll
        for (int p = 0; p < 4; p++) {
            float ox = (float)ovv[l][2 * p];
            float oy = (float)ovv[l][2 * p + 1];
            int ai = l * 4 + p;
            float a = (float)avv[ai >> 3][ai & 7];
            float x = (float)qx + ox;
            float y = (float)qy + oy;
            float xf = floorf(x), yf = floorf(y);
            int x0 = (int)xf, y0 = (int)yf;
            float wx1 = x - xf, wy1 = y - yf;
            float wx0 = 1.f - wx1, wy0 = 1.f - wy1;
            #pragma unroll
            for (int dy = 0; dy < 2; dy++) {
                int yc = y0 + dy;
                bool vy = (unsigned)yc < (unsigned)HH;
                int yci = min(max(yc, 0), HH - 1);
                float wyv = dy ? wy1 : wy0;
                #pragma unroll
                for (int dx = 0; dx < 2; dx++) {
                    int xc = x0 + dx;
                    bool vld = vy && ((unsigned)xc < (unsigned)WW);
                    int xci = min(max(xc, 0), WW - 1);
                    float wgt = vld ? a * wyv * (dx ? wx1 : wx0) : 0.f;
                    uint4 v = *(const uint4*)(vb + (size_t)(yci * WW + xci) * 16);
                    fma8(acc, wgt, v);
                }
            }
        }
    }
    uint4 o = { pk2(acc[0], acc[1]), pk2(acc[2], acc[3]),
                pk2(acc[4], acc[5]), pk2(acc[6], acc[7]) };
    *(uint4*)(out + (size_t)q * CCh + h * 16 + half * 8) = o;
}

// Bilinear 2x upsample -> padded NHWC bf16 (82,242,128), halo zeroed
__global__ void upsample_nhwc(const float* __restrict__ m, unsigned short* __restrict__ up)
{
    unsigned idx = blockIdx.x * 256u + threadIdx.x;   // < 82*242*32
    if (idx >= 82u * 242u * 32u) return;
    int c4 = (idx & 31) << 2;
    int p = idx >> 5;
    int px = p % 242, py = p / 242;
    ushort4 o = {0, 0, 0, 0};
    if (py >= 1 && py <= RHs && px >= 1 && px <= RWs) {
        int y = py - 1, x = px - 1;
        float fy = (y + 0.5f) * 0.5f - 0.5f;
        float fx = (x + 0.5f) * 0.5f - 0.5f;
        float fyf = floorf(fy), fxf = floorf(fx);
        int y0 = (int)fyf, x0 = (int)fxf;
        float wy = fy - fyf, wx = fx - fxf;
        int y0c = max(y0, 0), y1c = min(y0 + 1, HH - 1);
        int x0c = max(x0, 0), x1c = min(x0 + 1, WW - 1);
        unsigned short r[4];
        #pragma unroll
        for (int cc = 0; cc < 4; cc++) {
            const float* mp = m + (size_t)(c4 + cc) * HWp;
            float v00 = mp[y0c * WW + x0c], v01 = mp[y0c * WW + x1c];
            float v10 = mp[y1c * WW + x0c], v11 = mp[y1c * WW + x1c];
            float v = (1.f - wy) * ((1.f - wx) * v00 + wx * v01)
                    + wy * ((1.f - wx) * v10 + wx * v11);
            r[cc] = f2bf(v);
        }
        o.x = r[0]; o.y = r[1]; o.z = r[2]; o.w = r[3];
    }
    *(ushort4*)(up + (size_t)p * 128 + c4) = o;
}

// ---------------------------------------------------------------------------
extern "C" void kernel_launch(void* const* d_in, const int* in_sizes, int n_in,
                              void* d_out, int out_size, void* d_ws, size_t ws_size,
                              hipStream_t stream)
{
    const float* x       = (const float*)d_in[0];
    const float* dconv_w = (const float*)d_in[1];
    const float* dconv_b = (const float*)d_in[2];
    const float* lvl_emb = (const float*)d_in[3];
    const float* W_off   = (const float*)d_in[4];
    const float* b_off   = (const float*)d_in[5];
    const float* W_attn  = (const float*)d_in[6];
    const float* b_attn  = (const float*)d_in[7];
    const float* W_val   = (const float*)d_in[8];
    const float* b_val   = (const float*)d_in[9];
    const float* W_out   = (const float*)d_in[10];
    const float* b_out   = (const float*)d_in[11];
    const float* ln1_g   = (const float*)d_in[12];
    const float* ln1_b   = (const float*)d_in[13];
    const float* W_ff1   = (const float*)d_in[14];
    const float* b_ff1   = (const float*)d_in[15];
    const float* W_ff2   = (const float*)d_in[16];
    const float* b_ff2   = (const float*)d_in[17];
    const float* ln2_g   = (const float*)d_in[18];
    const float* ln2_b   = (const float*)d_in[19];
    const float* merge_w = (const float*)d_in[20];
    const float* merge_b = (const float*)d_in[21];
    const float* uconv_w = (const float*)d_in[22];
    const float* uconv_b = (const float*)d_in[23];

    char* wsb = (char*)d_ws;
    unsigned short* xp       = (unsigned short*)(wsb);               // 20,320,256 B (4,82,242,128)
    unsigned short* up       = (unsigned short*)(wsb + 20320256);    //  5,080,064 B (82,242,128)
    float*          src      = (float*)(wsb + 25400320);             //  9,830,400 B
    unsigned short* srcb     = (unsigned short*)(wsb + 35230720);    //  4,915,200 B
    float*          ty       = (float*)(wsb + 40145920);             //     10,240 B (40x64)
    float*          tx       = (float*)(wsb + 40156160);             //     30,720 B (120x64)
    unsigned short* qb       = (unsigned short*)(wsb + 49976320);    //  4,915,200 B
    unsigned short* valb     = (unsigned short*)(wsb + 54891520);    //  4,915,200 B
    _Float16*       attnh    = (_Float16*)(wsb + 59806720);          //  4,915,200 B
    unsigned short* attnoutb = (unsigned short*)(wsb + 69637120);    //  4,915,200 B
    unsigned short* wb       = (unsigned short*)(wsb + 104043520);   //  1,114,112 B
    unsigned short* dconv_wb = (unsigned short*)(wsb + 105452544);   //    294,912 B
    unsigned short* uconv_wb = (unsigned short*)(wsb + 105747456);   //    294,912 B
    unsigned short* wcat     = (unsigned short*)(wsb + 106042368);   //    294,912 B
    float*          bcat     = (float*)(wsb + 106337280);            //      4,608 B (end 106,341,888)
    // aliases (lifetimes disjoint):
    _Float16*       offh     = (_Float16*)xp;    // layers: xp dead after dconv gemm
    unsigned short* merge_in = up;               // written by layer-2 attn_ff; consumed before upsample writes up
    float*          mbuf     = (float*)valb;     // after layers
    float* outp = (float*)d_out;

    // bf16 linear weight table offsets (elements)
    unsigned short* W_val_b  = wb;
    unsigned short* W_out_b  = wb + 49152;
    unsigned short* W_ff1_b  = wb + 98304;
    unsigned short* W_ff2_b  = wb + 294912;
    unsigned short* merge_wb = wb + 491520;

    // 0) one-dispatch prep: weights, halo, pos tables, input transpose
    prep_all<<<5551, 256, 0, stream>>>(
        W_val, W_out, W_ff1, W_ff2, merge_w, W_off, b_off, W_attn, b_attn,
        dconv_w, uconv_w, x,
        wb, wcat, bcat, dconv_wb, uconv_wb, xp, ty, tx);

    // 1) downsample conv (implicit GEMM) -> src fp32 + srcb bf16 + qb, relu
    conv3x3_gemm<0><<<dim3(2, 300), 256, 0, stream>>>(
        xp, dconv_wb, dconv_b, src, srcb, ty, tx, lvl_emb, qb);

    // 2) encoder layers (3 dispatches each)
    for (int i = 0; i < 3; i++) {
        gemm_oav<<<dim3(8, 300), 256, 0, stream>>>(
            qb, srcb,
            wcat + (size_t)i * 49152, bcat + i * 384,
            W_val_b + (size_t)i * 16384, b_val + i * 128,
            offh, attnh, valb);
        deform_sample<<<1200, 256, 0, stream>>>(valb, offh, attnh, attnoutb);
        if (i < 2) {
            attn_ff<true, false><<<1200, 256, 0, stream>>>(
                attnoutb, src,
                W_out_b + (size_t)i * 16384, b_out + i * 128,
                ln1_g + i * 128, ln1_b + i * 128,
                W_ff1_b + (size_t)i * 65536, b_ff1 + i * 512,
                W_ff2_b + (size_t)i * 65536, b_ff2 + i * 128,
                ln2_g + i * 128, ln2_b + i * 128,
                src, srcb, ty, tx, lvl_emb, qb, nullptr);
        } else {
            attn_ff<false, true><<<1200, 256, 0, stream>>>(
                attnoutb, src,
                W_out_b + (size_t)i * 16384, b_out + i * 128,
                ln1_g + i * 128, ln1_b + i * 128,
                W_ff1_b + (size_t)i * 65536, b_ff1 + i * 512,
                W_ff2_b + (size_t)i * 65536, b_ff2 + i * 128,
                ln2_g + i * 128, ln2_b + i * 128,
                nullptr, nullptr, nullptr, nullptr, nullptr, nullptr, merge_in);
        }
    }

    // 3) merge 1x1 conv, weights-as-A trick: mbuf[128,4800], BM=64 (150 blocks)
    gemm_bf16<true, true, 0, 64><<<dim3(75, 2), 256, 0, stream>>>(
        merge_wb, merge_in, merge_b, mbuf, nullptr, 128, 4800, 512);

    // 4) bilinear 2x upsample -> padded NHWC bf16
    upsample_nhwc<<<2482, 256, 0, stream>>>(mbuf, up);

    // 5) uconv (implicit GEMM, transposed store) -> d_out (128,19200), relu
    conv3x3_gemm<1><<<dim3(2, 300), 256, 0, stream>>>(
        up, uconv_wb, uconv_b, outp, nullptr, nullptr, nullptr, nullptr, nullptr);
}

// Round 13
// 399.601 us; speedup vs baseline: 1.0608x; 1.0500x over previous
//
#include <hip/hip_runtime.h>
#include <math.h>
#include <cstddef>

// Problem constants
#define LQ   19200          // NL*H*W tokens
#define HH   40
#define WW   120
#define HWp  4800
#define CCh  128
#define NHd  8
#define NLv  4
#define NPt  4
#define RHs  80
#define RWs  240

typedef __attribute__((ext_vector_type(8))) short bf16x8;
typedef __attribute__((ext_vector_type(4))) float f32x4;
typedef __attribute__((ext_vector_type(8))) _Float16 h16x8;
typedef __attribute__((address_space(1))) const unsigned int GUI;
typedef __attribute__((address_space(3))) unsigned int LUI;

__device__ inline unsigned short f2bf(float f) {
    unsigned int u = __float_as_uint(f);
    u += 0x7fffu + ((u >> 16) & 1u);        // round-to-nearest-even
    return (unsigned short)(u >> 16);
}
__device__ inline float bf2f(unsigned int lo16) { return __uint_as_float(lo16 << 16); }

// sine pos-embed from small tables: pos(row, col) = tab + lvl_emb
__device__ inline float pos_eval(const float* __restrict__ ty,
                                 const float* __restrict__ tx,
                                 const float* __restrict__ lvl,
                                 int row, int col)
{
    int n = row / HWp, pix = row % HWp;
    int hh = pix / WW, wx = pix % WW;
    float t = (col < 64) ? ty[hh * 64 + col] : tx[wx * 64 + (col - 64)];
    return t + lvl[n * CCh + col];
}

__device__ inline void fma8(float* acc, float w, uint4 v)
{
    acc[0] = fmaf(w, __uint_as_float(v.x << 16),          acc[0]);
    acc[1] = fmaf(w, __uint_as_float(v.x & 0xffff0000u),  acc[1]);
    acc[2] = fmaf(w, __uint_as_float(v.y << 16),          acc[2]);
    acc[3] = fmaf(w, __uint_as_float(v.y & 0xffff0000u),  acc[3]);
    acc[4] = fmaf(w, __uint_as_float(v.z << 16),          acc[4]);
    acc[5] = fmaf(w, __uint_as_float(v.z & 0xffff0000u),  acc[5]);
    acc[6] = fmaf(w, __uint_as_float(v.w << 16),          acc[6]);
    acc[7] = fmaf(w, __uint_as_float(v.w & 0xffff0000u),  acc[7]);
}
__device__ inline unsigned int pk2(float a, float b)
{ return (unsigned int)f2bf(a) | ((unsigned int)f2bf(b) << 16); }

// ---------------------------------------------------------------------------
// bf16 MFMA GEMM: Out[M,N] = A[M,K] @ Bw[N,K]^T + bias, opt relu.
// Double-buffered LDS K-loop. BMD ∈ {64,128}: block-M tile.
// BIAS_ROW: bias indexed by row (weights-as-A transposed trick).
// OMODE: 0 = fp32 OutF; 1 = bf16 OutB; 2 = both.
// ---------------------------------------------------------------------------
template<bool BIAS_ROW, bool RELU, int OMODE, int BMD>
__global__ __launch_bounds__(256) void gemm_bf16(
    const unsigned short* __restrict__ A,
    const unsigned short* __restrict__ Bw,
    const float* __restrict__ bias,
    float* __restrict__ OutF, unsigned short* __restrict__ OutB,
    int M, int N, int K)
{
    constexpr int BN = 64, BK = 32;
    constexpr int MI = BMD / 32;                 // row-tiles per wave
    __shared__ unsigned short As[2][BMD * BK];   // row-major [m][k]
    __shared__ unsigned short Bs[2][BN * BK];
    const int bm = blockIdx.y * BMD, bn = blockIdx.x * BN;
    const int tid = threadIdx.x;
    const int wid = tid >> 6, lane = tid & 63;
    const int wm = (wid & 1) * (BMD / 2), wn = (wid >> 1) * 32;
    const int lm = lane & 15, lqd = lane >> 4;

    f32x4 acc[MI][2] = {};

    const int arow = lane >> 2;          // 0..15 within a 16-row chunk
    const int akc  = (lane & 3) * 8;     // k element offset (16 B granules)
    const unsigned short* aG0;
    const unsigned short* aG1 = nullptr;
    if constexpr (BMD == 128) {
        aG0 = A + (size_t)(bm + wid * 32 +      arow) * K + akc;
        aG1 = A + (size_t)(bm + wid * 32 + 16 + arow) * K + akc;
    } else {
        aG0 = A + (size_t)(bm + wid * 16 + arow) * K + akc;
    }
    const unsigned short* bG = Bw + (size_t)(bn + wid * 16 + arow) * K + akc;
    const int aoff = (BMD == 128) ? (wid * 1024 + lane * 8) : (wid * 512 + lane * 8);
    const int boff = wid * 512 + lane * 8;

    auto stage = [&](int b, int k0) {
        __builtin_amdgcn_global_load_lds((GUI*)(aG0 + k0), (LUI*)(As[b] + aoff), 16, 0, 0);
        if constexpr (BMD == 128)
            __builtin_amdgcn_global_load_lds((GUI*)(aG1 + k0), (LUI*)(As[b] + aoff + 512), 16, 0, 0);
        __builtin_amdgcn_global_load_lds((GUI*)(bG + k0), (LUI*)(Bs[b] + boff), 16, 0, 0);
    };

    stage(0, 0);
    __syncthreads();
    int buf = 0;
    for (int k0 = 0; k0 < K; k0 += BK, buf ^= 1) {
        if (k0 + BK < K) stage(buf ^ 1, k0 + BK);
        bf16x8 a[MI], b[2];
        #pragma unroll
        for (int i = 0; i < MI; i++)
            a[i] = *(const bf16x8*)(As[buf] + (wm + i * 16 + lm) * BK + lqd * 8);
        #pragma unroll
        for (int j = 0; j < 2; j++)
            b[j] = *(const bf16x8*)(Bs[buf] + (wn + j * 16 + lm) * BK + lqd * 8);
        #pragma unroll
        for (int i = 0; i < MI; i++)
            #pragma unroll
            for (int j = 0; j < 2; j++)
                acc[i][j] = __builtin_amdgcn_mfma_f32_16x16x32_bf16(a[i], b[j], acc[i][j], 0, 0, 0);
        __syncthreads();
    }

    #pragma unroll
    for (int i = 0; i < MI; i++) {
        int row0 = bm + wm + i * 16 + lqd * 4;
        #pragma unroll
        for (int j = 0; j < 2; j++) {
            int col = bn + wn + j * 16 + lm;
            float bc = BIAS_ROW ? 0.f : bias[col];
            #pragma unroll
            for (int r = 0; r < 4; r++) {
                int row = row0 + r;
                float v = acc[i][j][r] + (BIAS_ROW ? bias[row] : bc);
                if (RELU) v = fmaxf(v, 0.f);
                size_t o = (size_t)row * N + col;
                if (OMODE == 0) OutF[o] = v;
                else if (OMODE == 1) OutB[o] = f2bf(v);
                else { OutF[o] = v; OutB[o] = f2bf(v); }
            }
        }
    }
}

// ---------------------------------------------------------------------------
// Merged off/attn + val GEMM for one layer. Grid dim3(8, 300), BM=64, K=128.
// Double-buffered LDS. BM=64: latency hiding by block count (R8 lesson).
// bx<6: A=qb, W=Woa(384x128): col<256 -> fp16 off (stride 256);
//       col>=256 -> softmax16 -> fp16 attn (stride 128).
// bx>=6: A=srcb, W=Wv(128x128): bf16 val in plane layout [l][h][4800][16].
// ---------------------------------------------------------------------------
__global__ __launch_bounds__(256) void gemm_oav(
    const unsigned short* __restrict__ Aq,
    const unsigned short* __restrict__ Asrc,
    const unsigned short* __restrict__ Woa, const float* __restrict__ boa,
    const unsigned short* __restrict__ Wv,  const float* __restrict__ bv,
    _Float16* __restrict__ OutH, _Float16* __restrict__ OutH2,
    unsigned short* __restrict__ OutV)
{
    constexpr int BK = 32, K = 128;
    __shared__ unsigned short As[2][64 * BK];
    __shared__ unsigned short Bs[2][64 * BK];
    const int bx = blockIdx.x;
    const bool isv = bx >= 6;
    const unsigned short* A  = isv ? Asrc : Aq;
    const unsigned short* Bw = isv ? Wv : Woa;
    const float* bias = isv ? bv : boa;
    const int bn = isv ? (bx - 6) * 64 : bx * 64;
    const int bm = blockIdx.y * 64;
    const int tid = threadIdx.x;
    const int wid = tid >> 6, lane = tid & 63;
    const int wm = (wid & 1) * 32, wn = (wid >> 1) * 32;
    const int lm = lane & 15, lqd = lane >> 4;

    f32x4 acc[2][2] = {};

    const int arow = lane >> 2;
    const int akc  = (lane & 3) * 8;
    const unsigned short* aG = A  + (size_t)(bm + wid * 16 + arow) * K + akc;
    const unsigned short* bG = Bw + (size_t)(bn + wid * 16 + arow) * K + akc;
    const int loff = wid * 512 + lane * 8;

    auto stage = [&](int b, int k0) {
        __builtin_amdgcn_global_load_lds((GUI*)(aG + k0), (LUI*)(As[b] + loff), 16, 0, 0);
        __builtin_amdgcn_global_load_lds((GUI*)(bG + k0), (LUI*)(Bs[b] + loff), 16, 0, 0);
    };

    stage(0, 0);
    __syncthreads();
    int buf = 0;
    for (int k0 = 0; k0 < K; k0 += BK, buf ^= 1) {
        if (k0 + BK < K) stage(buf ^ 1, k0 + BK);
        bf16x8 a[2], b[2];
        #pragma unroll
        for (int i = 0; i < 2; i++)
            a[i] = *(const bf16x8*)(As[buf] + (wm + i * 16 + lm) * BK + lqd * 8);
        #pragma unroll
        for (int j = 0; j < 2; j++)
            b[j] = *(const bf16x8*)(Bs[buf] + (wn + j * 16 + lm) * BK + lqd * 8);
        #pragma unroll
        for (int i = 0; i < 2; i++)
            #pragma unroll
            for (int j = 0; j < 2; j++)
                acc[i][j] = __builtin_amdgcn_mfma_f32_16x16x32_bf16(a[i], b[j], acc[i][j], 0, 0, 0);
        __syncthreads();
    }

    #pragma unroll
    for (int i = 0; i < 2; i++) {
        int row0 = bm + wm + i * 16 + lqd * 4;
        #pragma unroll
        for (int j = 0; j < 2; j++) {
            int col = bn + wn + j * 16 + lm;
            float bc = bias[col];
            if (!isv) {
                if (col < 256) {
                    #pragma unroll
                    for (int r = 0; r < 4; r++)
                        OutH[(size_t)(row0 + r) * 256 + col] = (_Float16)(acc[i][j][r] + bc);
                } else {
                    #pragma unroll
                    for (int r = 0; r < 4; r++) {
                        float v = acc[i][j][r] + bc;
                        float m = v;
                        #pragma unroll
                        for (int msk = 1; msk < 16; msk <<= 1)
                            m = fmaxf(m, __shfl_xor(m, msk));
                        float e = __expf(v - m);
                        float s = e;
                        #pragma unroll
                        for (int msk = 1; msk < 16; msk <<= 1)
                            s += __shfl_xor(s, msk);
                        OutH2[(size_t)(row0 + r) * 128 + (col - 256)] = (_Float16)(e / s);
                    }
                }
            } else {
                #pragma unroll
                for (int r = 0; r < 4; r++) {
                    int row = row0 + r;
                    int plane = (row / HWp) * 8 + (col >> 4);
                    size_t o = ((size_t)plane * HWp + (row % HWp)) * 16 + (col & 15);
                    OutV[o] = f2bf(acc[i][j][r] + bc);
                }
            }
        }
    }
}

// ---------------------------------------------------------------------------
// FUSED deform-sample + post-attention block, 16 tokens/block (4 waves,
// grid 1200). Phase 0 performs the MS-deform bilinear gather for this
// block's 16 queries (thread = (q_local, head, half) = 16x8x2 = 256) and
// writes the 16x128 attnout tile to LDS (fs buffer, dead until phase B;
// the LN1 barrier separates the last phase-A read from phase-B's write).
// Eliminates the deform_sample dispatch and the attnoutb round-trip.
// Weights Wout/Wff1/Wff2 in MFMA FRAGMENT LAYOUT [n0][kc][lqd][lm][8].
//   attnout = gather(val, off, attn)                  (phase 0, LDS)
//   delta1 = attnout @ W_out^T + b_out
//   y1 = LayerNorm(src + delta1) * g1 + c1
//   for qc in 0..3: f = relu(y1 @ Wff1[qc]^T + b); delta2 += f @ Wff2[:,qc]^T
//   y2 = LayerNorm(y1 + delta2 + bff2) * g2 + c2
// WQ: also write qb = bf16(y2 + pos(row,col)) from ty/tx/lvl tables.
// WMERGE: write only merge-layout bf16 mergeb[pix][n*128+c] (final layer).
// ---------------------------------------------------------------------------
template<bool WQ, bool WMERGE>
__global__ __launch_bounds__(256) void attn_ff(
    const unsigned short* __restrict__ val, const _Float16* __restrict__ off,
    const _Float16* __restrict__ attn, const float* __restrict__ srcF_in,
    const unsigned short* __restrict__ Wout, const float* __restrict__ bout,
    const float* __restrict__ g1, const float* __restrict__ c1,
    const unsigned short* __restrict__ Wff1, const float* __restrict__ bff1,
    const unsigned short* __restrict__ Wff2, const float* __restrict__ bff2,
    const float* __restrict__ g2, const float* __restrict__ c2,
    float* __restrict__ outF, unsigned short* __restrict__ outB,
    const float* __restrict__ ty, const float* __restrict__ tx,
    const float* __restrict__ lvl, unsigned short* __restrict__ qb,
    unsigned short* __restrict__ mergeb)
{
    __shared__ unsigned short fs[16 * 136];     //  4,352 B: phase0 attnout tile, then ff chunk
    __shared__ unsigned short y1s[16 * 136];    //  4,352 B LN1 output (bf16)
    __shared__ float red[4][2][16];             //    512 B cross-wave LN partials
    const int bm = blockIdx.x * 16;
    const int tid = threadIdx.x;
    const int wid = tid >> 6, lane = tid & 63;
    const int lm = lane & 15, lqd = lane >> 4;
    const int wn2 = wid * 32;                   // col ownership, phases A & C

    // ---- Phase 0: MS-deform gather -> fs[ql][h*16 + half*8 .. +8]
    {
        int ql = tid >> 4;                 // 0..15
        int h  = (tid >> 1) & 7;           // 0..7
        int half = tid & 1;
        int q = bm + ql;
        int pix = q % HWp;
        int qy = pix / WW, qx = pix % WW;
        const _Float16* offp = off + (size_t)q * 256 + h * 32;
        const _Float16* ap   = attn + (size_t)q * 128 + h * 16;
        h16x8 ovv[4];
        ovv[0] = *(const h16x8*)(offp);
        ovv[1] = *(const h16x8*)(offp + 8);
        ovv[2] = *(const h16x8*)(offp + 16);
        ovv[3] = *(const h16x8*)(offp + 24);
        h16x8 avv[2];
        avv[0] = *(const h16x8*)(ap);
        avv[1] = *(const h16x8*)(ap + 8);
        const unsigned short* vh = val + half * 8;
        float acc[8] = {};
        #pragma unroll
        for (int l = 0; l < 4; l++) {
            const unsigned short* vb = vh + (size_t)(l * 8 + h) * (HWp * 16);
            #pragma unroll
            for (int p = 0; p < 4; p++) {
                float ox = (float)ovv[l][2 * p];
                float oy = (float)ovv[l][2 * p + 1];
                int ai = l * 4 + p;
                float a = (float)avv[ai >> 3][ai & 7];
                float x = (float)qx + ox;
                float y = (float)qy + oy;
                float xf = floorf(x), yf = floorf(y);
                int x0 = (int)xf, y0 = (int)yf;
                float wx1 = x - xf, wy1 = y - yf;
                float wx0 = 1.f - wx1, wy0 = 1.f - wy1;
                #pragma unroll
                for (int dy = 0; dy < 2; dy++) {
                    int yc = y0 + dy;
                    bool vy = (unsigned)yc < (unsigned)HH;
                    int yci = min(max(yc, 0), HH - 1);
                    float wyv = dy ? wy1 : wy0;
                    #pragma unroll
                    for (int dx = 0; dx < 2; dx++) {
                        int xc = x0 + dx;
                        bool vld = vy && ((unsigned)xc < (unsigned)WW);
                        int xci = min(max(xc, 0), WW - 1);
                        float wgt = vld ? a * wyv * (dx ? wx1 : wx0) : 0.f;
                        uint4 v = *(const uint4*)(vb + (size_t)(yci * WW + xci) * 16);
                        fma8(acc, wgt, v);
                    }
                }
            }
        }
        uint4 o = { pk2(acc[0], acc[1]), pk2(acc[2], acc[3]),
                    pk2(acc[4], acc[5]), pk2(acc[6], acc[7]) };
        *(uint4*)(fs + ql * 136 + h * 16 + half * 8) = o;
    }
    __syncthreads();

    // ---- Phase A: delta1 = attnout @ Wout^T (cols wn2..wn2+32)
    float y1r[2][4];
    {
        f32x4 accA[2] = {};
        for (int k0 = 0; k0 < 128; k0 += 32) {
            int kc = k0 >> 5;
            bf16x8 a = *(const bf16x8*)(fs + lm * 136 + k0 + lqd * 8);
            #pragma unroll
            for (int j = 0; j < 2; j++) {
                bf16x8 b = *(const bf16x8*)(Wout + ((size_t)((wid * 2 + j) * 4 + kc) * 64 + lane) * 8);
                accA[j] = __builtin_amdgcn_mfma_f32_16x16x32_bf16(a, b, accA[j], 0, 0, 0);
            }
        }
        #pragma unroll
        for (int j = 0; j < 2; j++) {
            int col = wn2 + j * 16 + lm;
            float bc = bout[col];
            #pragma unroll
            for (int r = 0; r < 4; r++) {
                int row = bm + lqd * 4 + r;
                y1r[j][r] = accA[j][r] + bc + srcF_in[(size_t)row * 128 + col];
            }
        }
    }
    // LN1 stats
    #pragma unroll
    for (int r = 0; r < 4; r++) {
        float s = y1r[0][r] + y1r[1][r];
        float q = y1r[0][r] * y1r[0][r] + y1r[1][r] * y1r[1][r];
        #pragma unroll
        for (int msk = 1; msk < 16; msk <<= 1) {
            s += __shfl_xor(s, msk);
            q += __shfl_xor(q, msk);
        }
        if (lm == 0) {
            int rl = lqd * 4 + r;
            red[wid][0][rl] = s;
            red[wid][1][rl] = q;
        }
    }
    __syncthreads();
    {
        float mean[4], inv[4];
        #pragma unroll
        for (int r = 0; r < 4; r++) {
            int rl = lqd * 4 + r;
            float s = red[0][0][rl] + red[1][0][rl] + red[2][0][rl] + red[3][0][rl];
            float q = red[0][1][rl] + red[1][1][rl] + red[2][1][rl] + red[3][1][rl];
            float m = s * (1.0f / 128.0f);
            float v = q * (1.0f / 128.0f) - m * m;
            mean[r] = m;
            inv[r] = rsqrtf(v + 1e-5f);
        }
        #pragma unroll
        for (int j = 0; j < 2; j++) {
            int col = wn2 + j * 16 + lm;
            float gc = g1[col], bc = c1[col];
            #pragma unroll
            for (int r = 0; r < 4; r++) {
                float y = (y1r[j][r] - mean[r]) * inv[r] * gc + bc;
                y1r[j][r] = y;
                y1s[(lqd * 4 + r) * 136 + col] = f2bf(y);
            }
        }
    }
    __syncthreads();   // covers: phase-A fs reads done; y1s visible

    // ---- Phases B+C, chunked over ff dim (4 chunks of 128)
    f32x4 acc2[2] = {};
    for (int qc = 0; qc < 4; qc++) {
        // Phase B chunk: f = relu(y1 @ Wff1[qc*128 + wid*32 ..]^T + b)
        {
            f32x4 accB[2] = {};
            for (int k0 = 0; k0 < 128; k0 += 32) {
                int kc = k0 >> 5;
                bf16x8 a = *(const bf16x8*)(y1s + lm * 136 + k0 + lqd * 8);
                #pragma unroll
                for (int j = 0; j < 2; j++) {
                    bf16x8 b = *(const bf16x8*)(Wff1 + ((size_t)((qc * 8 + wid * 2 + j) * 4 + kc) * 64 + lane) * 8);
                    accB[j] = __builtin_amdgcn_mfma_f32_16x16x32_bf16(a, b, accB[j], 0, 0, 0);
                }
            }
            #pragma unroll
            for (int j = 0; j < 2; j++) {
                int col = wid * 32 + j * 16 + lm;            // 0..127 within chunk
                float bc = bff1[qc * 128 + col];
                #pragma unroll
                for (int r = 0; r < 4; r++) {
                    int row = lqd * 4 + r;
                    fs[row * 136 + col] = f2bf(fmaxf(accB[j][r] + bc, 0.f));
                }
            }
        }
        __syncthreads();
        // Phase C chunk: acc2 += f @ Wff2[wn2.., qc*128..]^T
        for (int k0 = 0; k0 < 128; k0 += 32) {
            int kc = qc * 4 + (k0 >> 5);       // global k-chunk in K=512
            bf16x8 a = *(const bf16x8*)(fs + lm * 136 + k0 + lqd * 8);
            #pragma unroll
            for (int j = 0; j < 2; j++) {
                bf16x8 b = *(const bf16x8*)(Wff2 + ((size_t)((wid * 2 + j) * 16 + kc) * 64 + lane) * 8);
                acc2[j] = __builtin_amdgcn_mfma_f32_16x16x32_bf16(a, b, acc2[j], 0, 0, 0);
            }
        }
        __syncthreads();   // fs dead; next chunk may overwrite
    }

    // z2 = delta2 + bias + y1 (registers), LN2
    float z[2][4];
    #pragma unroll
    for (int j = 0; j < 2; j++) {
        int col = wn2 + j * 16 + lm;
        float bc = bff2[col];
        #pragma unroll
        for (int r = 0; r < 4; r++)
            z[j][r] = acc2[j][r] + bc + y1r[j][r];
    }
    #pragma unroll
    for (int r = 0; r < 4; r++) {
        float s = z[0][r] + z[1][r];
        float q = z[0][r] * z[0][r] + z[1][r] * z[1][r];
        #pragma unroll
        for (int msk = 1; msk < 16; msk <<= 1) {
            s += __shfl_xor(s, msk);
            q += __shfl_xor(q, msk);
        }
        if (lm == 0) {
            int rl = lqd * 4 + r;
            red[wid][0][rl] = s;
            red[wid][1][rl] = q;
        }
    }
    __syncthreads();

    {
        float mean[4], inv[4];
        #pragma unroll
        for (int r = 0; r < 4; r++) {
            int rl = lqd * 4 + r;
            float s = red[0][0][rl] + red[1][0][rl] + red[2][0][rl] + red[3][0][rl];
            float q = red[0][1][rl] + red[1][1][rl] + red[2][1][rl] + red[3][1][rl];
            float m = s * (1.0f / 128.0f);
            float v = q * (1.0f / 128.0f) - m * m;
            mean[r] = m;
            inv[r] = rsqrtf(v + 1e-5f);
        }
        #pragma unroll
        for (int j = 0; j < 2; j++) {
            int col = wn2 + j * 16 + lm;
            float gc = g2[col], bc2 = c2[col];
            #pragma unroll
            for (int r = 0; r < 4; r++) {
                int row = bm + lqd * 4 + r;
                float y = (z[j][r] - mean[r]) * inv[r] * gc + bc2;
                if constexpr (WMERGE) {
                    int n = row / HWp, pix = row % HWp;
                    mergeb[(size_t)pix * 512 + n * 128 + col] = f2bf(y);
                } else {
                    size_t o = (size_t)row * 128 + col;
                    outF[o] = y;
                    outB[o] = f2bf(y);
                    if constexpr (WQ)
                        qb[o] = f2bf(y + pos_eval(ty, tx, lvl, row, col));
                }
            }
        }
    }
}

// ---------------------------------------------------------------------------
// Implicit-GEMM 3x3 conv from padded NHWC bf16 input, tap-major weights.
// BM=64 (grid 2x300 = 600 blocks). Double-buffered LDS chunk loop.
// MODE 0: dconv  — X:(4,82,242,128), stride 2, out: src fp32 + srcb bf16 +
//                  qb = bf16(src+pos(tables)), relu.
// MODE 1: uconv  — X:(82,242,128), stride 1, out: d_out fp32 (128,19200)
//                  via LDS-transposed store, relu.
// ---------------------------------------------------------------------------
template<int MODE>
__global__ __launch_bounds__(256) void conv3x3_gemm(
    const unsigned short* __restrict__ X,
    const unsigned short* __restrict__ Wp,
    const float* __restrict__ bias,
    float* __restrict__ OutF, unsigned short* __restrict__ OutB,
    const float* __restrict__ ty, const float* __restrict__ tx,
    const float* __restrict__ lvl, unsigned short* __restrict__ Qb)
{
    constexpr int BM = 64, BN = 64, BK = 32;
    constexpr int SMEM = (MODE == 1) ? 17408 : 16384;   // dbuf A/B = 16 KB; Ts = 17,408 B
    __shared__ __align__(16) unsigned char smem[SMEM];
    unsigned short* As = (unsigned short*)smem;            // [2][64*32]
    unsigned short* Bs = (unsigned short*)(smem + 8192);   // [2][64*32]
    const int bm = blockIdx.y * BM, bn = blockIdx.x * BN;
    const int tid = threadIdx.x;
    const int wid = tid >> 6, lane = tid & 63;
    const int wm = (wid & 1) * 32, wn = (wid >> 1) * 32;
    const int lm = lane & 15, lqd = lane >> 4;

    f32x4 acc[2][2] = {};

    const int arow = lane >> 2;
    const int akc  = (lane & 3) * 8;
    const int r0 = bm + wid * 16 + arow;
    size_t bA0;
    if (MODE == 0) {
        int n0 = r0 / HWp, rem0 = r0 % HWp, oh0 = rem0 / WW, ow0 = rem0 % WW;
        bA0 = ((size_t)(n0 * 82 + oh0 * 2) * 242 + ow0 * 2) * 128;
    } else {
        int y0 = r0 / RWs, x0 = r0 % RWs;
        bA0 = ((size_t)y0 * 242 + x0) * 128;
    }
    const unsigned short* bG = Wp + (size_t)(bn + wid * 16 + arow) * 1152 + akc;
    const int loff = wid * 512 + lane * 8;

    auto stage = [&](int b, int c) {
        int tap = c >> 2;
        int cpart = (c & 3) << 5;
        int ky = tap / 3, kx = tap % 3;
        int toff = (ky * 242 + kx) * 128 + cpart + akc;
        __builtin_amdgcn_global_load_lds((GUI*)(X + bA0 + toff), (LUI*)(As + b * 2048 + loff), 16, 0, 0);
        __builtin_amdgcn_global_load_lds((GUI*)(bG + c * 32), (LUI*)(Bs + b * 2048 + loff), 16, 0, 0);
    };

    stage(0, 0);
    __syncthreads();
    int buf = 0;
    for (int chunk = 0; chunk < 36; chunk++, buf ^= 1) {
        if (chunk < 35) stage(buf ^ 1, chunk + 1);
        bf16x8 a[2], b[2];
        #pragma unroll
        for (int i = 0; i < 2; i++)
            a[i] = *(const bf16x8*)(As + buf * 2048 + (wm + i * 16 + lm) * BK + lqd * 8);
        #pragma unroll
        for (int j = 0; j < 2; j++)
            b[j] = *(const bf16x8*)(Bs + buf * 2048 + (wn + j * 16 + lm) * BK + lqd * 8);
        #pragma unroll
        for (int i = 0; i < 2; i++)
            #pragma unroll
            for (int j = 0; j < 2; j++)
                acc[i][j] = __builtin_amdgcn_mfma_f32_16x16x32_bf16(a[i], b[j], acc[i][j], 0, 0, 0);
        __syncthreads();
    }

    if (MODE == 0) {
        #pragma unroll
        for (int i = 0; i < 2; i++) {
            int row0 = bm + wm + i * 16 + lqd * 4;
            #pragma unroll
            for (int j = 0; j < 2; j++) {
                int col = bn + wn + j * 16 + lm;
                float bc = bias[col];
                #pragma unroll
                for (int r = 0; r < 4; r++) {
                    int row = row0 + r;
                    float v = fmaxf(acc[i][j][r] + bc, 0.f);
                    size_t o = (size_t)row * 128 + col;
                    OutF[o] = v;
                    OutB[o] = f2bf(v);
                    Qb[o] = f2bf(v + pos_eval(ty, tx, lvl, row, col));
                }
            }
        }
    } else {
        float* Ts = (float*)smem;                 // 64 ch x 68 pix floats
        #pragma unroll
        for (int i = 0; i < 2; i++) {
            int lr0 = wm + i * 16 + lqd * 4;
            #pragma unroll
            for (int j = 0; j < 2; j++) {
                int lc = wn + j * 16 + lm;
                float bc = bias[bn + lc];
                #pragma unroll
                for (int r = 0; r < 4; r++)
                    Ts[lc * 68 + lr0 + r] = fmaxf(acc[i][j][r] + bc, 0.f);
            }
        }
        __syncthreads();
        for (int f = tid; f < 64 * 16; f += 256) {
            int ch = f >> 4, p4 = (f & 15) << 2;
            float4 v4 = *(const float4*)(Ts + ch * 68 + p4);
            *(float4*)(OutF + (size_t)(bn + ch) * 19200 + bm + p4) = v4;
        }
    }
}

// ---------------------------------------------------------------------------
// One-dispatch prep: linear weights -> bf16 (Wout/Wff1/Wff2 in MFMA fragment
// layout [n0][kc][lqd][lm][8]), [W_off;W_attn] concat, conv weights
// tap-major, halo zero, pos sin/cos TABLES (ty 40x64, tx 120x64), and the
// NCHW->NHWC input transpose.
// ---------------------------------------------------------------------------
__global__ __launch_bounds__(256) void prep_all(
    const float* __restrict__ W_val, const float* __restrict__ W_out,
    const float* __restrict__ W_ff1, const float* __restrict__ W_ff2,
    const float* __restrict__ merge_w,
    const float* __restrict__ Woff, const float* __restrict__ boff,
    const float* __restrict__ Wattn, const float* __restrict__ battn,
    const float* __restrict__ dconv_w, const float* __restrict__ uconv_w,
    const float* __restrict__ x,
    unsigned short* __restrict__ wb, unsigned short* __restrict__ wcat,
    float* __restrict__ bcat, unsigned short* __restrict__ dconv_wb,
    unsigned short* __restrict__ uconv_wb, unsigned short* __restrict__ xp,
    float* __restrict__ ty, float* __restrict__ tx)
{
    __shared__ unsigned short t[240 * 36];       // used by transpose blocks only
    int blk = blockIdx.x;
    if (blk >= 4271) {
        // NCHW fp32 (4,128,80,240) -> padded NHWC bf16 (4,82,242,128)
        int b = blk - 4271;                      // < 1280: (n, y, 32-ch tile)
        int ct = b & 3;
        int tmp = b >> 2;
        int y = tmp % 80, n = tmp / 80;
        const float* xin = x + (((size_t)(n * 128 + ct * 32)) * 80 + y) * 240;
        for (int f = threadIdx.x; f < 32 * 240; f += 256) {
            int c = f / 240, xc = f % 240;
            t[xc * 36 + c] = f2bf(xin[(size_t)c * 19200 + xc]);
        }
        __syncthreads();
        unsigned short* out = xp + (((size_t)(n * 82 + y + 1)) * 242 + 1) * 128 + ct * 32;
        for (int f = threadIdx.x; f < 240 * 8; f += 256) {
            int xc = f >> 3, c4 = (f & 7) << 2;
            ushort4 v = *(const ushort4*)(t + xc * 36 + c4);
            *(ushort4*)(out + (size_t)xc * 128 + c4) = v;
        }
        return;
    }
    int idx = blk * 256 + threadIdx.x;
    if (idx < 557056) {
        if (idx < 49152) {
            wb[idx] = f2bf(W_val[idx]);                      // row-major (gemm_oav)
        } else if (idx < 98304) {
            int rel = idx - 49152;                           // W_out: N=128,K=128
            int layer = rel >> 14, within = rel & 16383;
            int n = within >> 7, k = within & 127;
            int frag = ((((n >> 4) * 4 + (k >> 5)) * 4 + ((k >> 3) & 3)) * 16 + (n & 15)) * 8 + (k & 7);
            wb[49152 + (layer << 14) + frag] = f2bf(W_out[rel]);
        } else if (idx < 294912) {
            int rel = idx - 98304;                           // W_ff1: N=512,K=128
            int layer = rel >> 16, within = rel & 65535;
            int n = within >> 7, k = within & 127;
            int frag = ((((n >> 4) * 4 + (k >> 5)) * 4 + ((k >> 3) & 3)) * 16 + (n & 15)) * 8 + (k & 7);
            wb[98304 + (layer << 16) + frag] = f2bf(W_ff1[rel]);
        } else if (idx < 491520) {
            int rel = idx - 294912;                          // W_ff2: N=128,K=512
            int layer = rel >> 16, within = rel & 65535;
            int n = within >> 9, k = within & 511;
            int frag = ((((n >> 4) * 16 + (k >> 5)) * 4 + ((k >> 3) & 3)) * 16 + (n & 15)) * 8 + (k & 7);
            wb[294912 + (layer << 16) + frag] = f2bf(W_ff2[rel]);
        } else {
            wb[idx] = f2bf(merge_w[idx - 491520]);           // row-major (gemm_bf16 A)
        }
    } else if (idx < 705664) {
        int j = idx - 557056;
        if (j < 147456) {
            int layer = j / 49152, r = (j / 128) % 384, c = j & 127;
            float v = (r < 256) ? Woff[((size_t)layer * 256 + r) * 128 + c]
                                : Wattn[((size_t)layer * 128 + (r - 256)) * 128 + c];
            wcat[j] = f2bf(v);
        } else if (j < 148608) {
            int k = j - 147456;
            int layer = k / 384, r = k % 384;
            bcat[k] = (r < 256) ? boff[layer * 256 + r] : battn[layer * 128 + (r - 256)];
        }
    } else if (idx < 853120) {
        int j = idx - 705664;
        int cout = j / 1152, k = j % 1152;
        int tap = k >> 7, cin = k & 127;
        dconv_wb[j] = f2bf(dconv_w[(cout * 128 + cin) * 9 + tap]);
    } else if (idx < 1000576) {
        int j = idx - 853120;
        int cout = j / 1152, k = j % 1152;
        int tap = k >> 7, cin = k & 127;
        uconv_wb[j] = f2bf(uconv_w[(cout * 128 + cin) * 9 + tap]);
    } else if (idx < 1083008) {
        int j = idx - 1000576;                 // < 4*644*32
        int c4 = (j & 31) << 2;
        int tt = j >> 5;
        int p = tt % 644, n = tt / 644;
        int y, xx;
        if (p < 242)      { y = 0;       xx = p;       }
        else if (p < 484) { y = 81;      xx = p - 242; }
        else if (p < 564) { y = p - 483; xx = 0;       }
        else              { y = p - 563; xx = 241;     }
        ushort4 z = {0, 0, 0, 0};
        *(ushort4*)(xp + (((size_t)(n * 82 + y)) * 242 + xx) * 128 + c4) = z;
    } else if (idx < 1093248) {
        int j = idx - 1083008;                 // < 10240: pos tables
        int cc = j & 63;
        float expo = (float)(cc & ~1) * (1.0f / 64.0f);
        float dim_t = __expf(expo * 9.2103403719761836f);   // 10000^expo
        if (j < 2560) {
            int hh = j >> 6;
            float e = (float)(hh + 1) / (40.0f + 1e-6f) * 6.283185307179586f;
            float p = e / dim_t;
            ty[j] = (cc & 1) ? __cosf(p) : __sinf(p);
        } else {
            int j2 = j - 2560;
            int wx = j2 >> 6;
            float e = (float)(wx + 1) / (120.0f + 1e-6f) * 6.283185307179586f;
            float p = e / dim_t;
            tx[j2] = (cc & 1) ? __cosf(p) : __sinf(p);
        }
    }
}

// Bilinear 2x upsample -> padded NHWC bf16 (82,242,128), halo zeroed
__global__ void upsample_nhwc(const float* __restrict__ m, unsigned short* __restrict__ up)
{
    unsigned idx = blockIdx.x * 256u + threadIdx.x;   // < 82*242*32
    if (idx >= 82u * 242u * 32u) return;
    int c4 = (idx & 31) << 2;
    int p = idx >> 5;
    int px = p % 242, py = p / 242;
    ushort4 o = {0, 0, 0, 0};
    if (py >= 1 && py <= RHs && px >= 1 && px <= RWs) {
        int y = py - 1, x = px - 1;
        float fy = (y + 0.5f) * 0.5f - 0.5f;
        float fx = (x + 0.5f) * 0.5f - 0.5f;
        float fyf = floorf(fy), fxf = floorf(fx);
        int y0 = (int)fyf, x0 = (int)fxf;
        float wy = fy - fyf, wx = fx - fxf;
        int y0c = max(y0, 0), y1c = min(y0 + 1, HH - 1);
        int x0c = max(x0, 0), x1c = min(x0 + 1, WW - 1);
        unsigned short r[4];
        #pragma unroll
        for (int cc = 0; cc < 4; cc++) {
            const float* mp = m + (size_t)(c4 + cc) * HWp;
            float v00 = mp[y0c * WW + x0c], v01 = mp[y0c * WW + x1c];
            float v10 = mp[y1c * WW + x0c], v11 = mp[y1c * WW + x1c];
            float v = (1.f - wy) * ((1.f - wx) * v00 + wx * v01)
                    + wy * ((1.f - wx) * v10 + wx * v11);
            r[cc] = f2bf(v);
        }
        o.x = r[0]; o.y = r[1]; o.z = r[2]; o.w = r[3];
    }
    *(ushort4*)(up + (size_t)p * 128 + c4) = o;
}

// ---------------------------------------------------------------------------
extern "C" void kernel_launch(void* const* d_in, const int* in_sizes, int n_in,
                              void* d_out, int out_size, void* d_ws, size_t ws_size,
                              hipStream_t stream)
{
    const float* x       = (const float*)d_in[0];
    const float* dconv_w = (const float*)d_in[1];
    const float* dconv_b = (const float*)d_in[2];
    const float* lvl_emb = (const float*)d_in[3];
    const float* W_off   = (const float*)d_in[4];
    const float* b_off   = (const float*)d_in[5];
    const float* W_attn  = (const float*)d_in[6];
    const float* b_attn  = (const float*)d_in[7];
    const float* W_val   = (const float*)d_in[8];
    const float* b_val   = (const float*)d_in[9];
    const float* W_out   = (const float*)d_in[10];
    const float* b_out   = (const float*)d_in[11];
    const float* ln1_g   = (const float*)d_in[12];
    const float* ln1_b   = (const float*)d_in[13];
    const float* W_ff1   = (const float*)d_in[14];
    const float* b_ff1   = (const float*)d_in[15];
    const float* W_ff2   = (const float*)d_in[16];
    const float* b_ff2   = (const float*)d_in[17];
    const float* ln2_g   = (const float*)d_in[18];
    const float* ln2_b   = (const float*)d_in[19];
    const float* merge_w = (const float*)d_in[20];
    const float* merge_b = (const float*)d_in[21];
    const float* uconv_w = (const float*)d_in[22];
    const float* uconv_b = (const float*)d_in[23];

    char* wsb = (char*)d_ws;
    unsigned short* xp       = (unsigned short*)(wsb);               // 20,320,256 B (4,82,242,128)
    unsigned short* up       = (unsigned short*)(wsb + 20320256);    //  5,080,064 B (82,242,128)
    float*          src      = (float*)(wsb + 25400320);             //  9,830,400 B
    unsigned short* srcb     = (unsigned short*)(wsb + 35230720);    //  4,915,200 B
    float*          ty       = (float*)(wsb + 40145920);             //     10,240 B (40x64)
    float*          tx       = (float*)(wsb + 40156160);             //     30,720 B (120x64)
    unsigned short* qb       = (unsigned short*)(wsb + 49976320);    //  4,915,200 B
    unsigned short* valb     = (unsigned short*)(wsb + 54891520);    //  4,915,200 B
    _Float16*       attnh    = (_Float16*)(wsb + 59806720);          //  4,915,200 B
    unsigned short* wb       = (unsigned short*)(wsb + 104043520);   //  1,114,112 B
    unsigned short* dconv_wb = (unsigned short*)(wsb + 105452544);   //    294,912 B
    unsigned short* uconv_wb = (unsigned short*)(wsb + 105747456);   //    294,912 B
    unsigned short* wcat     = (unsigned short*)(wsb + 106042368);   //    294,912 B
    float*          bcat     = (float*)(wsb + 106337280);            //      4,608 B (end 106,341,888)
    // aliases (lifetimes disjoint):
    _Float16*       offh     = (_Float16*)xp;    // layers: xp dead after dconv gemm
    unsigned short* merge_in = up;               // written by layer-2 attn_ff; consumed before upsample writes up
    float*          mbuf     = (float*)valb;     // after layers
    float* outp = (float*)d_out;

    // bf16 linear weight table offsets (elements)
    unsigned short* W_val_b  = wb;
    unsigned short* W_out_b  = wb + 49152;
    unsigned short* W_ff1_b  = wb + 98304;
    unsigned short* W_ff2_b  = wb + 294912;
    unsigned short* merge_wb = wb + 491520;

    // 0) one-dispatch prep: weights, halo, pos tables, input transpose
    prep_all<<<5551, 256, 0, stream>>>(
        W_val, W_out, W_ff1, W_ff2, merge_w, W_off, b_off, W_attn, b_attn,
        dconv_w, uconv_w, x,
        wb, wcat, bcat, dconv_wb, uconv_wb, xp, ty, tx);

    // 1) downsample conv (implicit GEMM) -> src fp32 + srcb bf16 + qb, relu
    conv3x3_gemm<0><<<dim3(2, 300), 256, 0, stream>>>(
        xp, dconv_wb, dconv_b, src, srcb, ty, tx, lvl_emb, qb);

    // 2) encoder layers (2 dispatches each: oav GEMM + fused deform/attn_ff)
    for (int i = 0; i < 3; i++) {
        gemm_oav<<<dim3(8, 300), 256, 0, stream>>>(
            qb, srcb,
            wcat + (size_t)i * 49152, bcat + i * 384,
            W_val_b + (size_t)i * 16384, b_val + i * 128,
            offh, attnh, valb);
        if (i < 2) {
            attn_ff<true, false><<<1200, 256, 0, stream>>>(
                valb, offh, attnh, src,
                W_out_b + (size_t)i * 16384, b_out + i * 128,
                ln1_g + i * 128, ln1_b + i * 128,
                W_ff1_b + (size_t)i * 65536, b_ff1 + i * 512,
                W_ff2_b + (size_t)i * 65536, b_ff2 + i * 128,
                ln2_g + i * 128, ln2_b + i * 128,
                src, srcb, ty, tx, lvl_emb, qb, nullptr);
        } else {
            attn_ff<false, true><<<1200, 256, 0, stream>>>(
                valb, offh, attnh, src,
                W_out_b + (size_t)i * 16384, b_out + i * 128,
                ln1_g + i * 128, ln1_b + i * 128,
                W_ff1_b + (size_t)i * 65536, b_ff1 + i * 512,
                W_ff2_b + (size_t)i * 65536, b_ff2 + i * 128,
                ln2_g + i * 128, ln2_b + i * 128,
                nullptr, nullptr, nullptr, nullptr, nullptr, nullptr, merge_in);
        }
    }

    // 3) merge 1x1 conv, weights-as-A trick: mbuf[128,4800], BM=64 (150 blocks)
    gemm_bf16<true, true, 0, 64><<<dim3(75, 2), 256, 0, stream>>>(
        merge_wb, merge_in, merge_b, mbuf, nullptr, 128, 4800, 512);

    // 4) bilinear 2x upsample -> padded NHWC bf16
    upsample_nhwc<<<2482, 256, 0, stream>>>(mbuf, up);

    // 5) uconv (implicit GEMM, transposed store) -> d_out (128,19200), relu
    conv3x3_gemm<1><<<dim3(2, 300), 256, 0, stream>>>(
        up, uconv_wb, uconv_b, outp, nullptr, nullptr, nullptr, nullptr, nullptr);
}